// Round 1
// baseline (6995.483 us; speedup 1.0000x reference)
//
#include <hip/hip_runtime.h>
#include <math.h>

// Problem constants
// B=4, S=1024, D=768, d_space=128, n_qk=1024, n_v=1024, n_know=4096, H=12, dh=64
#define TOK 4096

// Workspace layout (float offsets)
#define O_EMBN   0            // 6144*128 = 786432  normalized neuron_emb
#define O_XN     786432       // 3145728  xn1 ; later reused as attention output
#define O_HALL   3932160      // 1572864  h_all (4096x384) ; later h_know (4096x128)
#define O_TAU    5505024      // 12288    tau_attn (4096x3)
#define O_TAUK   5517312      // 4096     tau_know
#define O_GVQ    5521408      // 131072   gate vals Q   (know vals overlay GVQ..GVK)
#define O_GVK    5652480      // 131072   gate vals K
#define O_GVV    5783552      // 131072   gate vals V
#define O_GIQ    5914624      // 131072   gate idx Q    (know idx overlay GIQ..GIK)
#define O_GIK    6045696      // 131072
#define O_GIV    6176768      // 131072
#define O_QB     6307840      // 3145728  Q ; later xn2
#define O_KB     9453568      // 3145728  K
#define O_VB     12599296     // 3145728  V
#define O_SUM    15745024     // 7168: sumQ[1024], sumK[1024], sumV[1024], sumKnow[4096]
// total 15752192 floats = 63.0 MB

__global__ void k_zero(float* p, int n){
  int i = blockIdx.x*blockDim.x + threadIdx.x;
  if (i < n) p[i] = 0.f;
}

// normalize neuron_emb rows (6144 x 128)
__global__ void k_normemb(const float* __restrict__ e, float* __restrict__ o){
  int row = blockIdx.x; int t = threadIdx.x; // 128 threads
  float v = e[(size_t)row*128 + t];
  __shared__ float red[128];
  red[t] = v*v; __syncthreads();
  for (int s=64; s>0; s>>=1){ if (t<s) red[t]+=red[t+s]; __syncthreads(); }
  float norm = sqrtf(red[0]) + 1e-8f;
  o[(size_t)row*128 + t] = v / norm;
}

// layer norm over D=768, one token per block (256 threads)
__global__ void k_ln(const float* __restrict__ x, const float* __restrict__ sc,
                     const float* __restrict__ bi, float* __restrict__ o){
  int tok = blockIdx.x; int t = threadIdx.x;
  __shared__ float red[256];
  const float* xr = x + (size_t)tok*768;
  float a0=xr[t], a1=xr[t+256], a2=xr[t+512];
  red[t] = a0+a1+a2; __syncthreads();
  for (int s=128; s>0; s>>=1){ if (t<s) red[t]+=red[t+s]; __syncthreads(); }
  float mean = red[0] * (1.f/768.f);
  __syncthreads();
  float d0=a0-mean, d1=a1-mean, d2=a2-mean;
  red[t] = d0*d0+d1*d1+d2*d2; __syncthreads();
  for (int s=128; s>0; s>>=1){ if (t<s) red[t]+=red[t+s]; __syncthreads(); }
  float den = sqrtf(red[0]*(1.f/768.f) + 1e-6f);
  float* orow = o + (size_t)tok*768;
  orow[t]     = d0/den*sc[t]     + bi[t];
  orow[t+256] = d1/den*sc[t+256] + bi[t+256];
  orow[t+512] = d2/den*sc[t+512] + bi[t+512];
}

// out[tok, c] = xn[tok,:] @ W[:, c] + b[c]   (W is 768 x C, row-major)
// plus tau columns (tW 768 x tc), blockDim = C
__global__ void k_proj(const float* __restrict__ xn, const float* __restrict__ W,
                       const float* __restrict__ b, float* __restrict__ out, int C,
                       const float* __restrict__ tW, const float* __restrict__ tb,
                       float* __restrict__ tout, int tstride, int tc){
  int tok = blockIdx.x; int t = threadIdx.x;
  __shared__ float srow[768];
  const float* xr = xn + (size_t)tok*768;
  for (int d=t; d<768; d+=C) srow[d]=xr[d];
  __syncthreads();
  float o = b[t];
  for (int d=0; d<768; d++) o += srow[d]*W[(size_t)d*C + t];
  out[(size_t)tok*C + t] = o;
  if (t < tc){
    float o2 = tb[t];
    for (int d=0; d<768; d++) o2 += srow[d]*tW[(size_t)d*tc + t];
    tout[(size_t)tok*tstride + t] = o2;
  }
}

// threshold gate + top-K selection + normalization + aux atomic sums.
// h vector (128) at hbase[tok*hstride + hoff .. +128); tau scalar.
// low: n x 128 normalized embeddings. 256 threads/block, one token per block.
__global__ void k_gate(const float* __restrict__ hbase, int hstride, int hoff,
                       const float* __restrict__ taubase, int tstride, int toff,
                       const float* __restrict__ low, int n, int K,
                       float* __restrict__ gval, int* __restrict__ gidx,
                       float* __restrict__ sums){
  int tok = blockIdx.x; int t = threadIdx.x;
  __shared__ float sh[128];
  __shared__ float seg[4096];
  __shared__ float rv[256]; __shared__ int ri[256];
  __shared__ float sval[64]; __shared__ int sidx[64];
  __shared__ float sred[2];
  if (t < 128) sh[t] = hbase[(size_t)tok*hstride + hoff + t];
  __syncthreads();
  float tau = taubase[(size_t)tok*tstride + toff];
  int items = n >> 8;
  for (int i=0; i<items; i++){
    int j = t + (i<<8);
    const float* lr = low + (size_t)j*128;
    float s = 0.f;
    for (int d=0; d<128; d++) s += sh[d]*lr[d];
    float raw = s - tau;
    float g = raw > 0.f ? raw : 1e-8f*expf(raw);
    seg[j] = expf(g) - 1.0f;   // mimic reference exactly (NOT expm1f)
  }
  __syncthreads();
  for (int it=0; it<K; it++){
    float mv = -1.f; int mi = 0;
    for (int i=0; i<items; i++){
      int j = t + (i<<8);
      float v = seg[j];
      if (v > mv){ mv=v; mi=j; }
    }
    rv[t]=mv; ri[t]=mi; __syncthreads();
    for (int s=128; s>0; s>>=1){
      if (t<s && rv[t+s] > rv[t]){ rv[t]=rv[t+s]; ri[t]=ri[t+s]; }
      __syncthreads();
    }
    if (t==0){ sval[it]=rv[0]; sidx[it]=ri[0]; seg[ri[0]] = -1.f; }
    __syncthreads();
  }
  if (t==0){
    float s=0.f; for (int i=0;i<K;i++) s += sval[i];
    sred[0] = s + 1e-8f;          // gate_sum + EPS
    sred[1] = tanhf(sval[0]);     // gate_strength
  }
  __syncthreads();
  if (t < K){
    float nv = sval[t] / sred[0] * sred[1];
    gval[(size_t)tok*K + t] = nv;
    gidx[(size_t)tok*K + t] = sidx[t];
    atomicAdd(&sums[sidx[t]], nv);
  }
}

// sparse sense-emit: out[tok,:] (+)= sum_k (xn[tok,:]·emb[idx_k]) * gval_k * w[idx_k,:]
__global__ void k_sense(const float* __restrict__ xn, const float* __restrict__ emb,
                        const float* __restrict__ w, const float* __restrict__ gval,
                        const int* __restrict__ gidx, float* __restrict__ out,
                        int K, int acc){
  int tok = blockIdx.x; int t = threadIdx.x; // 256
  __shared__ float sxn[768]; __shared__ float sact[64]; __shared__ int sidx[64];
  const float* xr = xn + (size_t)tok*768;
  for (int d=t; d<768; d+=256) sxn[d]=xr[d];
  if (t < K) sidx[t] = gidx[(size_t)tok*K + t];
  __syncthreads();
  int tpk = 256 / K;               // 8 (K=32) or 4 (K=64)
  int k = t / tpk, p = t % tpk;
  const float* er = emb + (size_t)sidx[k]*768;
  float v = 0.f;
  for (int d=p; d<768; d+=tpk) v += sxn[d]*er[d];
  for (int off=tpk>>1; off; off>>=1) v += __shfl_down(v, off);
  if (p==0) sact[k] = v * gval[(size_t)tok*K + k];
  __syncthreads();
  float* orow = out + (size_t)tok*768;
  for (int d=t; d<768; d+=256){
    float o = 0.f;
    for (int kk=0; kk<K; kk++) o += sact[kk]*w[(size_t)sidx[kk]*768 + d];
    if (acc) orow[d] += o; else orow[d] = o;
  }
}

// causal attention, one (b, h, q-row) per 64-thread block; flash-style online softmax
__global__ void k_attn(const float* __restrict__ Q, const float* __restrict__ K,
                       const float* __restrict__ V, float* __restrict__ ao){
  int q = blockIdx.x, h = blockIdx.y, b = blockIdx.z;
  int lane = threadIdx.x;
  __shared__ float sq[64]; __shared__ float sp[64];
  size_t qtok = (size_t)b*1024 + q;
  sq[lane] = Q[qtok*768 + h*64 + lane];
  __syncthreads();
  float m = -INFINITY, l = 0.f, acc = 0.f;
  for (int t0 = 0; t0 <= q; t0 += 64){
    int tt = t0 + lane;
    float s = -INFINITY;
    if (tt <= q){
      const float* kr = K + ((size_t)b*1024 + tt)*768 + h*64;
      float d0 = 0.f;
      for (int d=0; d<64; d++) d0 += sq[d]*kr[d];
      s = d0 * 0.125f;   // 1/sqrt(64)
    }
    float cm = s;
    for (int off=32; off; off>>=1) cm = fmaxf(cm, __shfl_xor(cm, off));
    float mnew = fmaxf(m, cm);
    float p = (tt <= q) ? expf(s - mnew) : 0.f;
    float psum = p;
    for (int off=32; off; off>>=1) psum += __shfl_xor(psum, off);
    float scale = expf(m - mnew);
    l = l*scale + psum;
    __syncthreads(); sp[lane] = p; __syncthreads();
    float a = 0.f;
    int lim = min(64, q - t0 + 1);
    const float* vb = V + ((size_t)b*1024 + t0)*768 + h*64 + lane;
    for (int j=0; j<lim; j++) a += sp[j] * vb[(size_t)j*768];
    acc = acc*scale + a;
    m = mnew;
  }
  ao[qtok*768 + h*64 + lane] = acc / l;
}

// out[tok,:] = x[tok,:] + ao[tok,:] @ Wo  (Wo 768x768)
__global__ void k_expand(const float* __restrict__ x, const float* __restrict__ ao,
                         const float* __restrict__ Wo, float* __restrict__ out){
  int tok = blockIdx.x; int t = threadIdx.x; // 256
  __shared__ float srow[768];
  const float* ar = ao + (size_t)tok*768;
  for (int d=t; d<768; d+=256) srow[d]=ar[d];
  __syncthreads();
  for (int c=t; c<768; c+=256){
    float o = 0.f;
    for (int d=0; d<768; d++) o += srow[d]*Wo[(size_t)d*768 + c];
    out[(size_t)tok*768 + c] = x[(size_t)tok*768 + c] + o;
  }
}

// aux = sum over gate types of ((mean - t)^2).sum() * n
__global__ void k_aux(const float* __restrict__ sums, float* __restrict__ out){
  int t = threadIdx.x; // 256
  __shared__ float red[256];
  float a = 0.f;
  const float inv = 1.f/4096.f;   // 1/(B*S)
  const float tq = 1.f/1024.f;
  for (int j=t; j<1024; j+=256){
    float d0 = sums[j]*inv        - tq; a += d0*d0*1024.f;
    float d1 = sums[1024+j]*inv   - tq; a += d1*d1*1024.f;
    float d2 = sums[2048+j]*inv   - tq; a += d2*d2*1024.f;
  }
  const float tk = 1.f/4096.f;
  for (int j=t; j<4096; j+=256){
    float d3 = sums[3072+j]*inv - tk; a += d3*d3*4096.f;
  }
  red[t]=a; __syncthreads();
  for (int s=128; s>0; s>>=1){ if (t<s) red[t]+=red[t+s]; __syncthreads(); }
  if (t==0) out[0] = red[0];
}

extern "C" void kernel_launch(void* const* d_in, const int* in_sizes, int n_in,
                              void* d_out, int out_size, void* d_ws, size_t ws_size,
                              hipStream_t stream){
  const float* x        = (const float*)d_in[0];
  const float* qk_emb   = (const float*)d_in[1];
  const float* qk_w     = (const float*)d_in[2];
  const float* v_emb    = (const float*)d_in[3];
  const float* v_w      = (const float*)d_in[4];
  const float* know_emb = (const float*)d_in[5];
  const float* know_w   = (const float*)d_in[6];
  const float* neuron_emb = (const float*)d_in[7];
  const float* pak  = (const float*)d_in[8];
  const float* pab  = (const float*)d_in[9];
  const float* pkk  = (const float*)d_in[10];
  const float* pkb  = (const float*)d_in[11];
  const float* tak  = (const float*)d_in[12];
  const float* tab  = (const float*)d_in[13];
  const float* tkk  = (const float*)d_in[14];
  const float* tkb  = (const float*)d_in[15];
  const float* expO = (const float*)d_in[16];
  const float* ln1s = (const float*)d_in[17];
  const float* ln1b = (const float*)d_in[18];
  const float* ln2s = (const float*)d_in[19];
  const float* ln2b = (const float*)d_in[20];
  float* out = (float*)d_out;
  float* ws  = (float*)d_ws;

  k_zero<<<28,256,0,stream>>>(ws+O_SUM, 7168);
  k_normemb<<<6144,128,0,stream>>>(neuron_emb, ws+O_EMBN);
  k_ln<<<4096,256,0,stream>>>(x, ln1s, ln1b, ws+O_XN);
  k_proj<<<4096,384,0,stream>>>(ws+O_XN, pak, pab, ws+O_HALL, 384, tak, tab, ws+O_TAU, 3, 3);

  // attn gates: Q/K use qk_low (emb_norm rows 0..1023), V uses v_low (rows 1024..2047)
  k_gate<<<4096,256,0,stream>>>(ws+O_HALL,384,0,   ws+O_TAU,3,0, ws+O_EMBN,           1024,32, ws+O_GVQ,(int*)(ws+O_GIQ), ws+O_SUM);
  k_gate<<<4096,256,0,stream>>>(ws+O_HALL,384,128, ws+O_TAU,3,1, ws+O_EMBN,           1024,32, ws+O_GVK,(int*)(ws+O_GIK), ws+O_SUM+1024);
  k_gate<<<4096,256,0,stream>>>(ws+O_HALL,384,256, ws+O_TAU,3,2, ws+O_EMBN+1024*128,  1024,32, ws+O_GVV,(int*)(ws+O_GIV), ws+O_SUM+2048);

  k_sense<<<4096,256,0,stream>>>(ws+O_XN, qk_emb, qk_w, ws+O_GVQ,(int*)(ws+O_GIQ), ws+O_QB, 32,0);
  k_sense<<<4096,256,0,stream>>>(ws+O_XN, qk_emb, qk_w, ws+O_GVK,(int*)(ws+O_GIK), ws+O_KB, 32,0);
  k_sense<<<4096,256,0,stream>>>(ws+O_XN, v_emb,  v_w,  ws+O_GVV,(int*)(ws+O_GIV), ws+O_VB, 32,0);

  // attention writes into XN region (xn1 no longer needed)
  k_attn<<<dim3(1024,12,4),64,0,stream>>>(ws+O_QB, ws+O_KB, ws+O_VB, ws+O_XN);

  // x2 = x + attn_out @ expand_O  -> d_out (doubles as x2 buffer)
  k_expand<<<4096,256,0,stream>>>(x, ws+O_XN, expO, out);

  // LN2 -> xn2 in QB region
  k_ln<<<4096,256,0,stream>>>(out, ln2s, ln2b, ws+O_QB);
  k_proj<<<4096,128,0,stream>>>(ws+O_QB, pkk, pkb, ws+O_HALL, 128, tkk, tkb, ws+O_TAUK, 1, 1);

  // know gate over 4096 neurons, top-64 (know_low = emb_norm rows 2048..6143)
  k_gate<<<4096,256,0,stream>>>(ws+O_HALL,128,0, ws+O_TAUK,1,0, ws+O_EMBN+2048*128, 4096,64, ws+O_GVQ,(int*)(ws+O_GIQ), ws+O_SUM+3072);

  // know sense-emit accumulates into d_out
  k_sense<<<4096,256,0,stream>>>(ws+O_QB, know_emb, know_w, ws+O_GVQ,(int*)(ws+O_GIQ), out, 64,1);

  k_aux<<<1,256,0,stream>>>(ws+O_SUM, out + 3145728);
}

// Round 2
// 3019.663 us; speedup vs baseline: 2.3166x; 2.3166x over previous
//
#include <hip/hip_runtime.h>
#include <math.h>

// Problem constants
// B=4, S=1024, D=768, d_space=128, n_qk=1024, n_v=1024, n_know=4096, H=12, dh=64
#define TOK 4096

// Workspace layout (float offsets)
#define O_EMBN   0            // 6144*128 = 786432  normalized neuron_emb
#define O_XN     786432       // 3145728  xn1 ; later reused as attention output
#define O_HALL   3932160      // 1572864  h_all (4096x384) ; later h_know (4096x128)
#define O_TAU    5505024      // 12288    tau_attn (4096x3)
#define O_TAUK   5517312      // 4096     tau_know
#define O_GVQ    5521408      // 131072   gate vals Q   (know vals overlay GVQ)
#define O_GVK    5652480      // 131072   gate vals K
#define O_GVV    5783552      // 131072   gate vals V
#define O_GIQ    5914624      // 131072   gate idx Q    (know idx overlay GIQ)
#define O_GIK    6045696      // 131072
#define O_GIV    6176768      // 131072
#define O_QB     6307840      // 3145728  Q ; later xn2.  attn scores overlay QB..QB+4194304
#define O_KB     9453568      // 3145728  K.              know scores overlay KB..KB+4194304
#define O_VB     12599296     // 3145728  V
#define O_SUM    15745024     // 7168: sumQ[1024], sumK[1024], sumV[1024], sumKnow[4096]
// total 15752192 floats = 63.0 MB

__global__ void k_zero(float* p, int n){
  int i = blockIdx.x*blockDim.x + threadIdx.x;
  if (i < n) p[i] = 0.f;
}

// normalize neuron_emb rows (6144 x 128)
__global__ void k_normemb(const float* __restrict__ e, float* __restrict__ o){
  int row = blockIdx.x; int t = threadIdx.x; // 128 threads
  float v = e[(size_t)row*128 + t];
  __shared__ float red[128];
  red[t] = v*v; __syncthreads();
  for (int s=64; s>0; s>>=1){ if (t<s) red[t]+=red[t+s]; __syncthreads(); }
  float norm = sqrtf(red[0]) + 1e-8f;
  o[(size_t)row*128 + t] = v / norm;
}

// layer norm over D=768, one token per block (256 threads)
__global__ void k_ln(const float* __restrict__ x, const float* __restrict__ sc,
                     const float* __restrict__ bi, float* __restrict__ o){
  int tok = blockIdx.x; int t = threadIdx.x;
  __shared__ float red[256];
  const float* xr = x + (size_t)tok*768;
  float a0=xr[t], a1=xr[t+256], a2=xr[t+512];
  red[t] = a0+a1+a2; __syncthreads();
  for (int s=128; s>0; s>>=1){ if (t<s) red[t]+=red[t+s]; __syncthreads(); }
  float mean = red[0] * (1.f/768.f);
  __syncthreads();
  float d0=a0-mean, d1=a1-mean, d2=a2-mean;
  red[t] = d0*d0+d1*d1+d2*d2; __syncthreads();
  for (int s=128; s>0; s>>=1){ if (t<s) red[t]+=red[t+s]; __syncthreads(); }
  float den = sqrtf(red[0]*(1.f/768.f) + 1e-6f);
  float* orow = o + (size_t)tok*768;
  orow[t]     = d0/den*sc[t]     + bi[t];
  orow[t+256] = d1/den*sc[t+256] + bi[t+256];
  orow[t+512] = d2/den*sc[t+512] + bi[t+512];
}

// out[tok, c] = xn[tok,:] @ W[:, c] + b[c]   (W is 768 x C, row-major)
// plus tau columns (tW 768 x tc), blockDim = C
__global__ void k_proj(const float* __restrict__ xn, const float* __restrict__ W,
                       const float* __restrict__ b, float* __restrict__ out, int C,
                       const float* __restrict__ tW, const float* __restrict__ tb,
                       float* __restrict__ tout, int tstride, int tc){
  int tok = blockIdx.x; int t = threadIdx.x;
  __shared__ float srow[768];
  const float* xr = xn + (size_t)tok*768;
  for (int d=t; d<768; d+=C) srow[d]=xr[d];
  __syncthreads();
  float o = b[t];
  for (int d=0; d<768; d++) o += srow[d]*W[(size_t)d*C + t];
  out[(size_t)tok*C + t] = o;
  if (t < tc){
    float o2 = tb[t];
    for (int d=0; d<768; d++) o2 += srow[d]*tW[(size_t)d*tc + t];
    tout[(size_t)tok*tstride + t] = o2;
  }
}

// Tiled score GEMM + gate transform.
// Computes exp_gate[tok0+tt, nrow] for a 64-token x 64-neuron tile.
// h row = hbase[(tok)*hstride + hoff .. +128), low row = low[nrow*128 ..).
// outg is [chunk_tokens][n] row-major, tok index relative to tok0.
__global__ void k_score(const float* __restrict__ h, int hstride, int hoff,
                        const float* __restrict__ taub, int tstride, int toff,
                        const float* __restrict__ low,
                        float* __restrict__ outg, int n, int tok0){
  __shared__ float sh[64][129];
  __shared__ float sl[64][129];
  __shared__ float stau[64];
  int t = threadIdx.x;              // 256
  int nrow0 = blockIdx.x << 6;
  int trow0 = blockIdx.y << 6;      // within chunk
  #pragma unroll
  for (int k=0;k<8;k++){
    int idx = t + (k<<8);           // 0..2047 over (row, col4)
    int r = idx >> 5, c4 = (idx & 31) << 2;
    const float* src = h + (size_t)(tok0 + trow0 + r)*hstride + hoff + c4;
    float4 x4 = *(const float4*)src;
    sh[r][c4]=x4.x; sh[r][c4+1]=x4.y; sh[r][c4+2]=x4.z; sh[r][c4+3]=x4.w;
    const float* src2 = low + (size_t)(nrow0 + r)*128 + c4;
    float4 y4 = *(const float4*)src2;
    sl[r][c4]=y4.x; sl[r][c4+1]=y4.y; sl[r][c4+2]=y4.z; sl[r][c4+3]=y4.w;
  }
  if (t < 64) stau[t] = taub[(size_t)(tok0 + trow0 + t)*tstride + toff];
  __syncthreads();
  int ty = t >> 4, tx = t & 15;
  float acc[4][4] = {{0.f}};
  #pragma unroll 4
  for (int d=0; d<128; d++){
    float a0=sh[ty*4+0][d], a1=sh[ty*4+1][d], a2=sh[ty*4+2][d], a3=sh[ty*4+3][d];
    float b0=sl[tx*4+0][d], b1=sl[tx*4+1][d], b2=sl[tx*4+2][d], b3=sl[tx*4+3][d];
    acc[0][0]+=a0*b0; acc[0][1]+=a0*b1; acc[0][2]+=a0*b2; acc[0][3]+=a0*b3;
    acc[1][0]+=a1*b0; acc[1][1]+=a1*b1; acc[1][2]+=a1*b2; acc[1][3]+=a1*b3;
    acc[2][0]+=a2*b0; acc[2][1]+=a2*b1; acc[2][2]+=a2*b2; acc[2][3]+=a2*b3;
    acc[3][0]+=a3*b0; acc[3][1]+=a3*b1; acc[3][2]+=a3*b2; acc[3][3]+=a3*b3;
  }
  #pragma unroll
  for (int i=0;i<4;i++){
    int tt = trow0 + ty*4 + i;      // within chunk
    float tau = stau[ty*4+i];
    #pragma unroll
    for (int j=0;j<4;j++){
      float raw = acc[i][j] - tau;
      float g = raw > 0.f ? raw : 1e-8f*expf(raw);
      outg[(size_t)tt*n + nrow0 + tx*4 + j] = expf(g) - 1.0f;  // exact ref math
    }
  }
}

// Top-K selection from a score row held in registers; normalization + aux sums.
// ITEMS = n/256 (compile-time for static reg indexing), one token per block.
template<int ITEMS, int K>
__global__ void k_select(const float* __restrict__ sc, int n, int tok0,
                         float* __restrict__ gval, int* __restrict__ gidx,
                         float* __restrict__ sums){
  int tl = blockIdx.x; int t = threadIdx.x; // 256
  float v[ITEMS];
  const float* row = sc + (size_t)tl*n;
  #pragma unroll
  for (int i=0;i<ITEMS;i++) v[i] = row[t + (i<<8)];
  __shared__ float wv[4]; __shared__ int wi[4];
  __shared__ float s0; __shared__ float stot;
  float myval = 0.f; int myidx = 0;
  int w = t >> 6, lane = t & 63;
  for (int it=0; it<K; it++){
    float mv = v[0]; int mi = t;
    #pragma unroll
    for (int i=1;i<ITEMS;i++){
      float vi = v[i];
      if (vi > mv){ mv = vi; mi = t + (i<<8); }
    }
    // wave reduce, prefer lower index on equal value (top_k stability)
    #pragma unroll
    for (int off=32; off; off>>=1){
      float ov = __shfl_xor(mv, off);
      int   oi = __shfl_xor(mi, off);
      if (ov > mv || (ov == mv && oi < mi)){ mv = ov; mi = oi; }
    }
    if (lane==0){ wv[w]=mv; wi[w]=mi; }
    __syncthreads();
    float bv = wv[0]; int bi = wi[0];
    #pragma unroll
    for (int k=1;k<4;k++){
      float ov=wv[k]; int oi=wi[k];
      if (ov > bv || (ov == bv && oi < bi)){ bv=ov; bi=oi; }
    }
    if (t == (bi & 255)){
      #pragma unroll
      for (int i=0;i<ITEMS;i++) if (i == (bi >> 8)) v[i] = -1.f;
    }
    if (t == it){ myval = bv; myidx = bi; }
    if (it==0 && t==0) s0 = tanhf(bv);
    __syncthreads();
  }
  float c = (t < K) ? myval : 0.f;
  #pragma unroll
  for (int off=32; off; off>>=1) c += __shfl_xor(c, off);
  if (lane==0) wv[w]=c;
  __syncthreads();
  if (t==0) stot = wv[0]+wv[1]+wv[2]+wv[3] + 1e-8f;
  __syncthreads();
  if (t < K){
    float nv = myval / stot * s0;
    size_t o = (size_t)(tok0 + tl)*K + t;
    gval[o] = nv; gidx[o] = myidx;
    atomicAdd(&sums[myidx], nv);
  }
}

// sparse sense-emit: out[tok,:] (+)= sum_k (xn[tok,:]·emb[idx_k]) * gval_k * w[idx_k,:]
__global__ void k_sense(const float* __restrict__ xn, const float* __restrict__ emb,
                        const float* __restrict__ w, const float* __restrict__ gval,
                        const int* __restrict__ gidx, float* __restrict__ out,
                        int K, int acc){
  int tok = blockIdx.x; int t = threadIdx.x; // 256
  __shared__ float sxn[768]; __shared__ float sact[64]; __shared__ int sidx[64];
  const float* xr = xn + (size_t)tok*768;
  for (int d=t; d<768; d+=256) sxn[d]=xr[d];
  if (t < K) sidx[t] = gidx[(size_t)tok*K + t];
  __syncthreads();
  int tpk = 256 / K;               // 8 (K=32) or 4 (K=64)
  int k = t / tpk, p = t % tpk;
  const float* er = emb + (size_t)sidx[k]*768;
  float v = 0.f;
  for (int d=p; d<768; d+=tpk) v += sxn[d]*er[d];
  for (int off=tpk>>1; off; off>>=1) v += __shfl_down(v, off);
  if (p==0) sact[k] = v * gval[(size_t)tok*K + k];
  __syncthreads();
  float* orow = out + (size_t)tok*768;
  for (int d=t; d<768; d+=256){
    float o = 0.f;
    for (int kk=0; kk<K; kk++) o += sact[kk]*w[(size_t)sidx[kk]*768 + d];
    if (acc) orow[d] += o; else orow[d] = o;
  }
}

// causal attention, one (b, h, q-row) per 64-thread block; flash-style online softmax
__global__ void k_attn(const float* __restrict__ Q, const float* __restrict__ K,
                       const float* __restrict__ V, float* __restrict__ ao){
  int q = blockIdx.x, h = blockIdx.y, b = blockIdx.z;
  int lane = threadIdx.x;
  __shared__ float sq[64]; __shared__ float sp[64];
  size_t qtok = (size_t)b*1024 + q;
  sq[lane] = Q[qtok*768 + h*64 + lane];
  __syncthreads();
  float m = -INFINITY, l = 0.f, acc = 0.f;
  for (int t0 = 0; t0 <= q; t0 += 64){
    int tt = t0 + lane;
    float s = -INFINITY;
    if (tt <= q){
      const float* kr = K + ((size_t)b*1024 + tt)*768 + h*64;
      float d0 = 0.f;
      for (int d=0; d<64; d++) d0 += sq[d]*kr[d];
      s = d0 * 0.125f;   // 1/sqrt(64)
    }
    float cm = s;
    for (int off=32; off; off>>=1) cm = fmaxf(cm, __shfl_xor(cm, off));
    float mnew = fmaxf(m, cm);
    float p = (tt <= q) ? expf(s - mnew) : 0.f;
    float psum = p;
    for (int off=32; off; off>>=1) psum += __shfl_xor(psum, off);
    float scale = expf(m - mnew);
    l = l*scale + psum;
    __syncthreads(); sp[lane] = p; __syncthreads();
    float a = 0.f;
    int lim = min(64, q - t0 + 1);
    const float* vb = V + ((size_t)b*1024 + t0)*768 + h*64 + lane;
    for (int j=0; j<lim; j++) a += sp[j] * vb[(size_t)j*768];
    acc = acc*scale + a;
    m = mnew;
  }
  ao[qtok*768 + h*64 + lane] = acc / l;
}

// out[tok,:] = x[tok,:] + ao[tok,:] @ Wo  (Wo 768x768)
__global__ void k_expand(const float* __restrict__ x, const float* __restrict__ ao,
                         const float* __restrict__ Wo, float* __restrict__ out){
  int tok = blockIdx.x; int t = threadIdx.x; // 256
  __shared__ float srow[768];
  const float* ar = ao + (size_t)tok*768;
  for (int d=t; d<768; d+=256) srow[d]=ar[d];
  __syncthreads();
  for (int c=t; c<768; c+=256){
    float o = 0.f;
    for (int d=0; d<768; d++) o += srow[d]*Wo[(size_t)d*768 + c];
    out[(size_t)tok*768 + c] = x[(size_t)tok*768 + c] + o;
  }
}

// aux = sum over gate types of ((mean - t)^2).sum() * n
__global__ void k_aux(const float* __restrict__ sums, float* __restrict__ out){
  int t = threadIdx.x; // 256
  __shared__ float red[256];
  float a = 0.f;
  const float inv = 1.f/4096.f;   // 1/(B*S)
  const float tq = 1.f/1024.f;
  for (int j=t; j<1024; j+=256){
    float d0 = sums[j]*inv        - tq; a += d0*d0*1024.f;
    float d1 = sums[1024+j]*inv   - tq; a += d1*d1*1024.f;
    float d2 = sums[2048+j]*inv   - tq; a += d2*d2*1024.f;
  }
  const float tk = 1.f/4096.f;
  for (int j=t; j<4096; j+=256){
    float d3 = sums[3072+j]*inv - tk; a += d3*d3*4096.f;
  }
  red[t]=a; __syncthreads();
  for (int s=128; s>0; s>>=1){ if (t<s) red[t]+=red[t+s]; __syncthreads(); }
  if (t==0) out[0] = red[0];
}

extern "C" void kernel_launch(void* const* d_in, const int* in_sizes, int n_in,
                              void* d_out, int out_size, void* d_ws, size_t ws_size,
                              hipStream_t stream){
  const float* x        = (const float*)d_in[0];
  const float* qk_emb   = (const float*)d_in[1];
  const float* qk_w     = (const float*)d_in[2];
  const float* v_emb    = (const float*)d_in[3];
  const float* v_w      = (const float*)d_in[4];
  const float* know_emb = (const float*)d_in[5];
  const float* know_w   = (const float*)d_in[6];
  const float* neuron_emb = (const float*)d_in[7];
  const float* pak  = (const float*)d_in[8];
  const float* pab  = (const float*)d_in[9];
  const float* pkk  = (const float*)d_in[10];
  const float* pkb  = (const float*)d_in[11];
  const float* tak  = (const float*)d_in[12];
  const float* tab  = (const float*)d_in[13];
  const float* tkk  = (const float*)d_in[14];
  const float* tkb  = (const float*)d_in[15];
  const float* expO = (const float*)d_in[16];
  const float* ln1s = (const float*)d_in[17];
  const float* ln1b = (const float*)d_in[18];
  const float* ln2s = (const float*)d_in[19];
  const float* ln2b = (const float*)d_in[20];
  float* out = (float*)d_out;
  float* ws  = (float*)d_ws;

  k_zero<<<28,256,0,stream>>>(ws+O_SUM, 7168);
  k_normemb<<<6144,128,0,stream>>>(neuron_emb, ws+O_EMBN);
  k_ln<<<4096,256,0,stream>>>(x, ln1s, ln1b, ws+O_XN);
  k_proj<<<4096,384,0,stream>>>(ws+O_XN, pak, pab, ws+O_HALL, 384, tak, tab, ws+O_TAU, 3, 3);

  // ---- attn gates: score (tiled GEMM) + select (register top-K) ----
  // scores (4096x1024 fp32 = 16MB) overlay QB region (Q/K/V not yet written)
  float* sc = ws + O_QB;
  // Q gate
  k_score<<<dim3(16,64),256,0,stream>>>(ws+O_HALL,384,0,   ws+O_TAU,3,0, ws+O_EMBN, sc, 1024, 0);
  k_select<4,32><<<4096,256,0,stream>>>(sc, 1024, 0, ws+O_GVQ,(int*)(ws+O_GIQ), ws+O_SUM);
  // K gate
  k_score<<<dim3(16,64),256,0,stream>>>(ws+O_HALL,384,128, ws+O_TAU,3,1, ws+O_EMBN, sc, 1024, 0);
  k_select<4,32><<<4096,256,0,stream>>>(sc, 1024, 0, ws+O_GVK,(int*)(ws+O_GIK), ws+O_SUM+1024);
  // V gate (v_low = emb_norm rows 1024..2047)
  k_score<<<dim3(16,64),256,0,stream>>>(ws+O_HALL,384,256, ws+O_TAU,3,2, ws+O_EMBN+1024*128, sc, 1024, 0);
  k_select<4,32><<<4096,256,0,stream>>>(sc, 1024, 0, ws+O_GVV,(int*)(ws+O_GIV), ws+O_SUM+2048);

  k_sense<<<4096,256,0,stream>>>(ws+O_XN, qk_emb, qk_w, ws+O_GVQ,(int*)(ws+O_GIQ), ws+O_QB, 32,0);
  k_sense<<<4096,256,0,stream>>>(ws+O_XN, qk_emb, qk_w, ws+O_GVK,(int*)(ws+O_GIK), ws+O_KB, 32,0);
  k_sense<<<4096,256,0,stream>>>(ws+O_XN, v_emb,  v_w,  ws+O_GVV,(int*)(ws+O_GIV), ws+O_VB, 32,0);

  // attention writes into XN region (xn1 no longer needed)
  k_attn<<<dim3(1024,12,4),64,0,stream>>>(ws+O_QB, ws+O_KB, ws+O_VB, ws+O_XN);

  // x2 = x + attn_out @ expand_O  -> d_out (doubles as x2 buffer)
  k_expand<<<4096,256,0,stream>>>(x, ws+O_XN, expO, out);

  // LN2 -> xn2 in QB region
  k_ln<<<4096,256,0,stream>>>(out, ln2s, ln2b, ws+O_QB);
  k_proj<<<4096,128,0,stream>>>(ws+O_QB, pkk, pkb, ws+O_HALL, 128, tkk, tkb, ws+O_TAUK, 1, 1);

  // ---- know gate: 4 chunks of 1024 tokens; scores (1024x4096 = 16MB) overlay KB region ----
  float* sck = ws + O_KB;
  for (int c=0; c<4; c++){
    int tok0 = c*1024;
    k_score<<<dim3(64,16),256,0,stream>>>(ws+O_HALL,128,0, ws+O_TAUK,1,0, ws+O_EMBN+2048*128, sck, 4096, tok0);
    k_select<16,64><<<1024,256,0,stream>>>(sck, 4096, tok0, ws+O_GVQ,(int*)(ws+O_GIQ), ws+O_SUM+3072);
  }

  // know sense-emit accumulates into d_out
  k_sense<<<4096,256,0,stream>>>(ws+O_QB, know_emb, know_w, ws+O_GVQ,(int*)(ws+O_GIQ), out, 64,1);

  k_aux<<<1,256,0,stream>>>(ws+O_SUM, out + 3145728);
}

// Round 3
// 2064.819 us; speedup vs baseline: 3.3879x; 1.4624x over previous
//
#include <hip/hip_runtime.h>
#include <math.h>

// Problem constants
// B=4, S=1024, D=768, d_space=128, n_qk=1024, n_v=1024, n_know=4096, H=12, dh=64
#define TOK 4096

// Workspace layout (float offsets)
#define O_EMBN   0            // 6144*128 = 786432  normalized neuron_emb
#define O_XN     786432       // 3145728  xn1 ; later reused as attention output
#define O_HALL   3932160      // 1572864  h_all (4096x384) ; later h_know (4096x128)
#define O_TAU    5505024      // 12288    tau_attn (4096x3)
#define O_TAUK   5517312      // 4096     tau_know
#define O_GVQ    5521408      // 131072   gate vals Q   (know vals overlay GVQ)
#define O_GVK    5652480      // 131072   gate vals K
#define O_GVV    5783552      // 131072   gate vals V
#define O_GIQ    5914624      // 131072   gate idx Q    (know idx overlay GIQ)
#define O_GIK    6045696      // 131072
#define O_GIV    6176768      // 131072
#define O_QB     6307840      // 3145728  Q ; later xn2.  attn scores overlay QB..QB+4194304
#define O_KB     9453568      // 3145728  K.              know scores overlay KB..KB+4194304
#define O_VB     12599296     // 3145728  V
#define O_SUM    15745024     // 7168: sumQ[1024], sumK[1024], sumV[1024], sumKnow[4096]
// total 15752192 floats = 63.0 MB

__global__ void k_zero(float* p, int n){
  int i = blockIdx.x*blockDim.x + threadIdx.x;
  if (i < n) p[i] = 0.f;
}

// normalize neuron_emb rows (6144 x 128)
__global__ void k_normemb(const float* __restrict__ e, float* __restrict__ o){
  int row = blockIdx.x; int t = threadIdx.x; // 128 threads
  float v = e[(size_t)row*128 + t];
  __shared__ float red[128];
  red[t] = v*v; __syncthreads();
  for (int s=64; s>0; s>>=1){ if (t<s) red[t]+=red[t+s]; __syncthreads(); }
  float norm = sqrtf(red[0]) + 1e-8f;
  o[(size_t)row*128 + t] = v / norm;
}

// layer norm over D=768, one token per block (256 threads)
__global__ void k_ln(const float* __restrict__ x, const float* __restrict__ sc,
                     const float* __restrict__ bi, float* __restrict__ o){
  int tok = blockIdx.x; int t = threadIdx.x;
  __shared__ float red[256];
  const float* xr = x + (size_t)tok*768;
  float a0=xr[t], a1=xr[t+256], a2=xr[t+512];
  red[t] = a0+a1+a2; __syncthreads();
  for (int s=128; s>0; s>>=1){ if (t<s) red[t]+=red[t+s]; __syncthreads(); }
  float mean = red[0] * (1.f/768.f);
  __syncthreads();
  float d0=a0-mean, d1=a1-mean, d2=a2-mean;
  red[t] = d0*d0+d1*d1+d2*d2; __syncthreads();
  for (int s=128; s>0; s>>=1){ if (t<s) red[t]+=red[t+s]; __syncthreads(); }
  float den = sqrtf(red[0]*(1.f/768.f) + 1e-6f);
  float* orow = o + (size_t)tok*768;
  orow[t]     = d0/den*sc[t]     + bi[t];
  orow[t+256] = d1/den*sc[t+256] + bi[t+256];
  orow[t+512] = d2/den*sc[t+512] + bi[t+512];
}

// Tiled GEMM: out[M x N] = A[M x 768] @ W[768 x N] (+bias) (+res with stride 768)
// grid (N/64, M/64), 256 threads, 64x64 tiles, K staged in 64-chunks.
template<bool RES>
__global__ void k_gemm(const float* __restrict__ A, const float* __restrict__ W,
                       const float* __restrict__ bias, const float* __restrict__ res,
                       float* __restrict__ out, int N){
  __shared__ float sA[64][65];
  __shared__ float sW[64][65];
  int t = threadIdx.x;
  int nc0 = blockIdx.x << 6;
  int m0  = blockIdx.y << 6;
  int ty = t >> 4, tx = t & 15;
  float acc[4][4] = {{0.f}};
  for (int kc=0; kc<768; kc+=64){
    __syncthreads();
    #pragma unroll
    for (int i=0;i<4;i++){
      int idx = t + (i<<8); int r = idx>>4, c4=(idx&15)<<2;
      float4 a4 = *(const float4*)(A + (size_t)(m0+r)*768 + kc + c4);
      sA[r][c4]=a4.x; sA[r][c4+1]=a4.y; sA[r][c4+2]=a4.z; sA[r][c4+3]=a4.w;
      float4 w4 = *(const float4*)(W + (size_t)(kc+r)*N + nc0 + c4);
      sW[r][c4]=w4.x; sW[r][c4+1]=w4.y; sW[r][c4+2]=w4.z; sW[r][c4+3]=w4.w;
    }
    __syncthreads();
    #pragma unroll 4
    for (int d=0; d<64; d++){
      float a0=sA[ty*4+0][d], a1=sA[ty*4+1][d], a2=sA[ty*4+2][d], a3=sA[ty*4+3][d];
      float b0=sW[d][tx*4+0], b1=sW[d][tx*4+1], b2=sW[d][tx*4+2], b3=sW[d][tx*4+3];
      acc[0][0]+=a0*b0; acc[0][1]+=a0*b1; acc[0][2]+=a0*b2; acc[0][3]+=a0*b3;
      acc[1][0]+=a1*b0; acc[1][1]+=a1*b1; acc[1][2]+=a1*b2; acc[1][3]+=a1*b3;
      acc[2][0]+=a2*b0; acc[2][1]+=a2*b1; acc[2][2]+=a2*b2; acc[2][3]+=a2*b3;
      acc[3][0]+=a3*b0; acc[3][1]+=a3*b1; acc[3][2]+=a3*b2; acc[3][3]+=a3*b3;
    }
  }
  #pragma unroll
  for (int i=0;i<4;i++){
    int row = m0 + ty*4 + i;
    #pragma unroll
    for (int j=0;j<4;j++){
      int col = nc0 + tx*4 + j;
      float v = acc[i][j];
      if (bias) v += bias[col];
      if (RES)  v += res[(size_t)row*768 + col];
      out[(size_t)row*N + col] = v;
    }
  }
}

// tau matvec: tout[tok, col] = xn[tok,:] @ tW[:, col] + tb[col]; 64*tc threads
__global__ void k_tau(const float* __restrict__ xn, const float* __restrict__ tW,
                      const float* __restrict__ tb, float* __restrict__ tout, int tc){
  int tok = blockIdx.x;
  int t = threadIdx.x;
  int col = t >> 6, lane = t & 63;
  const float* xr = xn + (size_t)tok*768;
  float v = 0.f;
  for (int d=lane; d<768; d+=64) v += xr[d]*tW[(size_t)d*tc + col];
  #pragma unroll
  for (int off=32; off; off>>=1) v += __shfl_down(v, off);
  if (lane==0) tout[(size_t)tok*tc + col] = v + tb[col];
}

// Tiled score GEMM + gate transform (64 tokens x 64 neurons per block).
__global__ void k_score(const float* __restrict__ h, int hstride, int hoff,
                        const float* __restrict__ taub, int tstride, int toff,
                        const float* __restrict__ low,
                        float* __restrict__ outg, int n, int tok0){
  __shared__ float sh[64][129];
  __shared__ float sl[64][129];
  __shared__ float stau[64];
  int t = threadIdx.x;              // 256
  int nrow0 = blockIdx.x << 6;
  int trow0 = blockIdx.y << 6;      // within chunk
  #pragma unroll
  for (int k=0;k<8;k++){
    int idx = t + (k<<8);           // 0..2047 over (row, col4)
    int r = idx >> 5, c4 = (idx & 31) << 2;
    const float* src = h + (size_t)(tok0 + trow0 + r)*hstride + hoff + c4;
    float4 x4 = *(const float4*)src;
    sh[r][c4]=x4.x; sh[r][c4+1]=x4.y; sh[r][c4+2]=x4.z; sh[r][c4+3]=x4.w;
    const float* src2 = low + (size_t)(nrow0 + r)*128 + c4;
    float4 y4 = *(const float4*)src2;
    sl[r][c4]=y4.x; sl[r][c4+1]=y4.y; sl[r][c4+2]=y4.z; sl[r][c4+3]=y4.w;
  }
  if (t < 64) stau[t] = taub[(size_t)(tok0 + trow0 + t)*tstride + toff];
  __syncthreads();
  int ty = t >> 4, tx = t & 15;
  float acc[4][4] = {{0.f}};
  #pragma unroll 4
  for (int d=0; d<128; d++){
    float a0=sh[ty*4+0][d], a1=sh[ty*4+1][d], a2=sh[ty*4+2][d], a3=sh[ty*4+3][d];
    float b0=sl[tx*4+0][d], b1=sl[tx*4+1][d], b2=sl[tx*4+2][d], b3=sl[tx*4+3][d];
    acc[0][0]+=a0*b0; acc[0][1]+=a0*b1; acc[0][2]+=a0*b2; acc[0][3]+=a0*b3;
    acc[1][0]+=a1*b0; acc[1][1]+=a1*b1; acc[1][2]+=a1*b2; acc[1][3]+=a1*b3;
    acc[2][0]+=a2*b0; acc[2][1]+=a2*b1; acc[2][2]+=a2*b2; acc[2][3]+=a2*b3;
    acc[3][0]+=a3*b0; acc[3][1]+=a3*b1; acc[3][2]+=a3*b2; acc[3][3]+=a3*b3;
  }
  #pragma unroll
  for (int i=0;i<4;i++){
    int tt = trow0 + ty*4 + i;      // within chunk
    float tau = stau[ty*4+i];
    #pragma unroll
    for (int j=0;j<4;j++){
      float raw = acc[i][j] - tau;
      float g = raw > 0.f ? raw : 1e-8f*expf(raw);
      outg[(size_t)tt*n + nrow0 + tx*4 + j] = expf(g) - 1.0f;  // exact ref math
    }
  }
}

// Top-K selection from a score row held in registers; normalization + aux sums.
template<int ITEMS, int K>
__global__ void k_select(const float* __restrict__ sc, int n, int tok0,
                         float* __restrict__ gval, int* __restrict__ gidx,
                         float* __restrict__ sums){
  int tl = blockIdx.x; int t = threadIdx.x; // 256
  float v[ITEMS];
  const float* row = sc + (size_t)tl*n;
  #pragma unroll
  for (int i=0;i<ITEMS;i++) v[i] = row[t + (i<<8)];
  __shared__ float wv[4]; __shared__ int wi[4];
  __shared__ float s0; __shared__ float stot;
  float myval = 0.f; int myidx = 0;
  int w = t >> 6, lane = t & 63;
  for (int it=0; it<K; it++){
    float mv = v[0]; int mi = t;
    #pragma unroll
    for (int i=1;i<ITEMS;i++){
      float vi = v[i];
      if (vi > mv){ mv = vi; mi = t + (i<<8); }
    }
    #pragma unroll
    for (int off=32; off; off>>=1){
      float ov = __shfl_xor(mv, off);
      int   oi = __shfl_xor(mi, off);
      if (ov > mv || (ov == mv && oi < mi)){ mv = ov; mi = oi; }
    }
    if (lane==0){ wv[w]=mv; wi[w]=mi; }
    __syncthreads();
    float bv = wv[0]; int bi = wi[0];
    #pragma unroll
    for (int k=1;k<4;k++){
      float ov=wv[k]; int oi=wi[k];
      if (ov > bv || (ov == bv && oi < bi)){ bv=ov; bi=oi; }
    }
    if (t == (bi & 255)){
      #pragma unroll
      for (int i=0;i<ITEMS;i++) if (i == (bi >> 8)) v[i] = -1.f;
    }
    if (t == it){ myval = bv; myidx = bi; }
    if (it==0 && t==0) s0 = tanhf(bv);
    __syncthreads();
  }
  float c = (t < K) ? myval : 0.f;
  #pragma unroll
  for (int off=32; off; off>>=1) c += __shfl_xor(c, off);
  if (lane==0) wv[w]=c;
  __syncthreads();
  if (t==0) stot = wv[0]+wv[1]+wv[2]+wv[3] + 1e-8f;
  __syncthreads();
  if (t < K){
    float nv = myval / stot * s0;
    size_t o = (size_t)(tok0 + tl)*K + t;
    gval[o] = nv; gidx[o] = myidx;
    atomicAdd(&sums[myidx], nv);
  }
}

// sparse sense-emit: out[tok,:] (+)= sum_k (xn[tok,:]·emb[idx_k]) * gval_k * w[idx_k,:]
__global__ void k_sense(const float* __restrict__ xn, const float* __restrict__ emb,
                        const float* __restrict__ w, const float* __restrict__ gval,
                        const int* __restrict__ gidx, float* __restrict__ out,
                        int K, int acc){
  int tok = blockIdx.x; int t = threadIdx.x; // 256
  __shared__ float sxn[768]; __shared__ float sact[64]; __shared__ int sidx[64];
  const float* xr = xn + (size_t)tok*768;
  for (int d=t; d<768; d+=256) sxn[d]=xr[d];
  if (t < K) sidx[t] = gidx[(size_t)tok*K + t];
  __syncthreads();
  int tpk = 256 / K;               // 8 (K=32) or 4 (K=64)
  int k = t / tpk, p = t % tpk;
  const float* er = emb + (size_t)sidx[k]*768;
  float v = 0.f;
  for (int d=p; d<768; d+=tpk) v += sxn[d]*er[d];
  for (int off=tpk>>1; off; off>>=1) v += __shfl_down(v, off);
  if (p==0) sact[k] = v * gval[(size_t)tok*K + k];
  __syncthreads();
  float* orow = out + (size_t)tok*768;
  for (int d=t; d<768; d+=256){
    float o = 0.f;
    for (int kk=0; kk<K; kk++) o += sact[kk]*w[(size_t)sidx[kk]*768 + d];
    if (acc) orow[d] += o; else orow[d] = o;
  }
}

// Tiled causal flash attention: one block = 64 q-rows x one head.
// grid (16, 12, 4) with qt reversed for heavy-first dispatch; 256 threads.
__global__ void k_attn(const float* __restrict__ Q, const float* __restrict__ K,
                       const float* __restrict__ V, float* __restrict__ ao){
  __shared__ float sQ[64][65];
  __shared__ float sKV[64][65];   // K tile, then V tile (time-shared)
  __shared__ float sP[64][65];
  int qt = gridDim.x - 1 - blockIdx.x;
  int h = blockIdx.y, b = blockIdx.z;
  int t = threadIdx.x;
  int ty = t >> 4, tx = t & 15;
  size_t base = ((size_t)b*1024)*768 + (size_t)h*64;
  int q0 = qt << 6;
  #pragma unroll
  for (int i=0;i<4;i++){
    int idx = t + (i<<8); int r = idx>>4, c4 = (idx&15)<<2;
    float4 v4 = *(const float4*)(Q + base + (size_t)(q0+r)*768 + c4);
    sQ[r][c4]=v4.x; sQ[r][c4+1]=v4.y; sQ[r][c4+2]=v4.z; sQ[r][c4+3]=v4.w;
  }
  float m[4], l[4], o[4][4];
  #pragma unroll
  for (int r=0;r<4;r++){
    m[r] = -INFINITY; l[r] = 0.f;
    #pragma unroll
    for (int c=0;c<4;c++) o[r][c] = 0.f;
  }
  for (int kt=0; kt<=qt; kt++){
    int t0 = kt << 6;
    __syncthreads();                 // prev PV done with sP / sKV
    #pragma unroll
    for (int i=0;i<4;i++){
      int idx = t + (i<<8); int r = idx>>4, c4=(idx&15)<<2;
      float4 kv = *(const float4*)(K + base + (size_t)(t0+r)*768 + c4);
      sKV[r][c4]=kv.x; sKV[r][c4+1]=kv.y; sKV[r][c4+2]=kv.z; sKV[r][c4+3]=kv.w;
    }
    __syncthreads();
    float s[4][4] = {{0.f}};
    #pragma unroll 4
    for (int d=0; d<64; d++){
      float a0=sQ[ty*4+0][d], a1=sQ[ty*4+1][d], a2=sQ[ty*4+2][d], a3=sQ[ty*4+3][d];
      float b0=sKV[tx*4+0][d], b1=sKV[tx*4+1][d], b2=sKV[tx*4+2][d], b3=sKV[tx*4+3][d];
      s[0][0]+=a0*b0; s[0][1]+=a0*b1; s[0][2]+=a0*b2; s[0][3]+=a0*b3;
      s[1][0]+=a1*b0; s[1][1]+=a1*b1; s[1][2]+=a1*b2; s[1][3]+=a1*b3;
      s[2][0]+=a2*b0; s[2][1]+=a2*b1; s[2][2]+=a2*b2; s[2][3]+=a2*b3;
      s[3][0]+=a3*b0; s[3][1]+=a3*b1; s[3][2]+=a3*b2; s[3][3]+=a3*b3;
    }
    bool diag = (kt == qt);
    #pragma unroll
    for (int r=0;r<4;r++){
      #pragma unroll
      for (int c=0;c<4;c++){
        s[r][c] *= 0.125f;           // 1/sqrt(64)
        if (diag && (tx*4+c > ty*4+r)) s[r][c] = -INFINITY;
      }
    }
    float scl[4];
    #pragma unroll
    for (int r=0;r<4;r++){
      float tm = fmaxf(fmaxf(s[r][0],s[r][1]), fmaxf(s[r][2],s[r][3]));
      #pragma unroll
      for (int off=8; off; off>>=1) tm = fmaxf(tm, __shfl_xor(tm, off));
      float mn = fmaxf(m[r], tm);
      float sc = expf(m[r] - mn);    // m=-inf first tile -> 0
      float ps = 0.f;
      #pragma unroll
      for (int c=0;c<4;c++){
        float p = expf(s[r][c] - mn);
        s[r][c] = p; ps += p;
        sP[ty*4+r][tx*4+c] = p;
      }
      #pragma unroll
      for (int off=8; off; off>>=1) ps += __shfl_xor(ps, off);
      l[r] = l[r]*sc + ps;
      m[r] = mn;
      scl[r] = sc;
    }
    #pragma unroll
    for (int r=0;r<4;r++){
      #pragma unroll
      for (int c=0;c<4;c++) o[r][c] *= scl[r];
    }
    __syncthreads();                 // sP visible, everyone done with sKV(K)
    #pragma unroll
    for (int i=0;i<4;i++){
      int idx = t + (i<<8); int r = idx>>4, c4=(idx&15)<<2;
      float4 vv = *(const float4*)(V + base + (size_t)(t0+r)*768 + c4);
      sKV[r][c4]=vv.x; sKV[r][c4+1]=vv.y; sKV[r][c4+2]=vv.z; sKV[r][c4+3]=vv.w;
    }
    __syncthreads();
    #pragma unroll 4
    for (int k=0;k<64;k++){
      float p0=sP[ty*4+0][k], p1=sP[ty*4+1][k], p2=sP[ty*4+2][k], p3=sP[ty*4+3][k];
      float v0=sKV[k][tx*4+0], v1=sKV[k][tx*4+1], v2=sKV[k][tx*4+2], v3=sKV[k][tx*4+3];
      o[0][0]+=p0*v0; o[0][1]+=p0*v1; o[0][2]+=p0*v2; o[0][3]+=p0*v3;
      o[1][0]+=p1*v0; o[1][1]+=p1*v1; o[1][2]+=p1*v2; o[1][3]+=p1*v3;
      o[2][0]+=p2*v0; o[2][1]+=p2*v1; o[2][2]+=p2*v2; o[2][3]+=p2*v3;
      o[3][0]+=p3*v0; o[3][1]+=p3*v1; o[3][2]+=p3*v2; o[3][3]+=p3*v3;
    }
  }
  #pragma unroll
  for (int r=0;r<4;r++){
    float inv = 1.f / l[r];
    #pragma unroll
    for (int c=0;c<4;c++)
      ao[base + (size_t)(q0+ty*4+r)*768 + tx*4+c] = o[r][c]*inv;
  }
}

// aux = sum over gate types of ((mean - t)^2).sum() * n
__global__ void k_aux(const float* __restrict__ sums, float* __restrict__ out){
  int t = threadIdx.x; // 256
  __shared__ float red[256];
  float a = 0.f;
  const float inv = 1.f/4096.f;   // 1/(B*S)
  const float tq = 1.f/1024.f;
  for (int j=t; j<1024; j+=256){
    float d0 = sums[j]*inv        - tq; a += d0*d0*1024.f;
    float d1 = sums[1024+j]*inv   - tq; a += d1*d1*1024.f;
    float d2 = sums[2048+j]*inv   - tq; a += d2*d2*1024.f;
  }
  const float tk = 1.f/4096.f;
  for (int j=t; j<4096; j+=256){
    float d3 = sums[3072+j]*inv - tk; a += d3*d3*4096.f;
  }
  red[t]=a; __syncthreads();
  for (int s=128; s>0; s>>=1){ if (t<s) red[t]+=red[t+s]; __syncthreads(); }
  if (t==0) out[0] = red[0];
}

extern "C" void kernel_launch(void* const* d_in, const int* in_sizes, int n_in,
                              void* d_out, int out_size, void* d_ws, size_t ws_size,
                              hipStream_t stream){
  const float* x        = (const float*)d_in[0];
  const float* qk_emb   = (const float*)d_in[1];
  const float* qk_w     = (const float*)d_in[2];
  const float* v_emb    = (const float*)d_in[3];
  const float* v_w      = (const float*)d_in[4];
  const float* know_emb = (const float*)d_in[5];
  const float* know_w   = (const float*)d_in[6];
  const float* neuron_emb = (const float*)d_in[7];
  const float* pak  = (const float*)d_in[8];
  const float* pab  = (const float*)d_in[9];
  const float* pkk  = (const float*)d_in[10];
  const float* pkb  = (const float*)d_in[11];
  const float* tak  = (const float*)d_in[12];
  const float* tab  = (const float*)d_in[13];
  const float* tkk  = (const float*)d_in[14];
  const float* tkb  = (const float*)d_in[15];
  const float* expO = (const float*)d_in[16];
  const float* ln1s = (const float*)d_in[17];
  const float* ln1b = (const float*)d_in[18];
  const float* ln2s = (const float*)d_in[19];
  const float* ln2b = (const float*)d_in[20];
  float* out = (float*)d_out;
  float* ws  = (float*)d_ws;

  k_zero<<<28,256,0,stream>>>(ws+O_SUM, 7168);
  k_normemb<<<6144,128,0,stream>>>(neuron_emb, ws+O_EMBN);
  k_ln<<<4096,256,0,stream>>>(x, ln1s, ln1b, ws+O_XN);
  k_gemm<false><<<dim3(6,64),256,0,stream>>>(ws+O_XN, pak, pab, nullptr, ws+O_HALL, 384);
  k_tau<<<4096,192,0,stream>>>(ws+O_XN, tak, tab, ws+O_TAU, 3);

  // ---- attn gates: score (tiled GEMM) + select (register top-K) ----
  float* sc = ws + O_QB;
  k_score<<<dim3(16,64),256,0,stream>>>(ws+O_HALL,384,0,   ws+O_TAU,3,0, ws+O_EMBN, sc, 1024, 0);
  k_select<4,32><<<4096,256,0,stream>>>(sc, 1024, 0, ws+O_GVQ,(int*)(ws+O_GIQ), ws+O_SUM);
  k_score<<<dim3(16,64),256,0,stream>>>(ws+O_HALL,384,128, ws+O_TAU,3,1, ws+O_EMBN, sc, 1024, 0);
  k_select<4,32><<<4096,256,0,stream>>>(sc, 1024, 0, ws+O_GVK,(int*)(ws+O_GIK), ws+O_SUM+1024);
  k_score<<<dim3(16,64),256,0,stream>>>(ws+O_HALL,384,256, ws+O_TAU,3,2, ws+O_EMBN+1024*128, sc, 1024, 0);
  k_select<4,32><<<4096,256,0,stream>>>(sc, 1024, 0, ws+O_GVV,(int*)(ws+O_GIV), ws+O_SUM+2048);

  k_sense<<<4096,256,0,stream>>>(ws+O_XN, qk_emb, qk_w, ws+O_GVQ,(int*)(ws+O_GIQ), ws+O_QB, 32,0);
  k_sense<<<4096,256,0,stream>>>(ws+O_XN, qk_emb, qk_w, ws+O_GVK,(int*)(ws+O_GIK), ws+O_KB, 32,0);
  k_sense<<<4096,256,0,stream>>>(ws+O_XN, v_emb,  v_w,  ws+O_GVV,(int*)(ws+O_GIV), ws+O_VB, 32,0);

  // attention writes into XN region (xn1 no longer needed)
  k_attn<<<dim3(16,12,4),256,0,stream>>>(ws+O_QB, ws+O_KB, ws+O_VB, ws+O_XN);

  // x2 = x + attn_out @ expand_O  -> d_out (doubles as x2 buffer)
  k_gemm<true><<<dim3(12,64),256,0,stream>>>(ws+O_XN, expO, nullptr, x, out, 768);

  // LN2 -> xn2 in QB region
  k_ln<<<4096,256,0,stream>>>(out, ln2s, ln2b, ws+O_QB);
  k_gemm<false><<<dim3(2,64),256,0,stream>>>(ws+O_QB, pkk, pkb, nullptr, ws+O_HALL, 128);
  k_tau<<<4096,64,0,stream>>>(ws+O_QB, tkk, tkb, ws+O_TAUK, 1);

  // ---- know gate: 4 chunks of 1024 tokens; scores overlay KB region ----
  float* sck = ws + O_KB;
  for (int c=0; c<4; c++){
    int tok0 = c*1024;
    k_score<<<dim3(64,16),256,0,stream>>>(ws+O_HALL,128,0, ws+O_TAUK,1,0, ws+O_EMBN+2048*128, sck, 4096, tok0);
    k_select<16,64><<<1024,256,0,stream>>>(sck, 4096, tok0, ws+O_GVQ,(int*)(ws+O_GIQ), ws+O_SUM+3072);
  }

  // know sense-emit accumulates into d_out
  k_sense<<<4096,256,0,stream>>>(ws+O_QB, know_emb, know_w, ws+O_GVQ,(int*)(ws+O_GIQ), out, 64,1);

  k_aux<<<1,256,0,stream>>>(ws+O_SUM, out + 3145728);
}

// Round 6
// 1855.267 us; speedup vs baseline: 3.7706x; 1.1129x over previous
//
#include <hip/hip_runtime.h>
#include <math.h>

// Problem constants
// B=4, S=1024, D=768, d_space=128, n_qk=1024, n_v=1024, n_know=4096, H=12, dh=64
#define TOK 4096

// Workspace layout (float offsets)
#define O_EMBN   0            // 6144*128 = 786432  normalized neuron_emb
#define O_XN     786432       // 3145728  xn1 ; later reused as attention output
#define O_HALL   3932160      // 1572864  h_all (4096x384) ; later h_know (4096x128)
#define O_TAU    5505024      // 12288    tau_attn (4096x3)
#define O_TAUK   5517312      // 4096     tau_know
#define O_GVQ    5521408      // 131072   gate vals Q   (know vals overlay GVQ)
#define O_GVK    5652480      // 131072   gate vals K
#define O_GVV    5783552      // 131072   gate vals V
#define O_GIQ    5914624      // 131072   gate idx Q    (know idx overlay GIQ)
#define O_GIK    6045696      // 131072
#define O_GIV    6176768      // 131072
#define O_QB     6307840      // 3145728  Q ; later xn2.  attn scores overlay QB..QB+4194304
#define O_KB     9453568      // 3145728  K.              know scores overlay KB..KB+4194304
#define O_VB     12599296     // 3145728  V
#define O_SUM    15745024     // 7168: sumQ[1024], sumK[1024], sumV[1024], sumKnow[4096]
// total 15752192 floats = 63.0 MB

__global__ void k_zero(float* p, int n){
  int i = blockIdx.x*blockDim.x + threadIdx.x;
  if (i < n) p[i] = 0.f;
}

// normalize neuron_emb rows (6144 x 128)
__global__ void k_normemb(const float* __restrict__ e, float* __restrict__ o){
  int row = blockIdx.x; int t = threadIdx.x; // 128 threads
  float v = e[(size_t)row*128 + t];
  __shared__ float red[128];
  red[t] = v*v; __syncthreads();
  for (int s=64; s>0; s>>=1){ if (t<s) red[t]+=red[t+s]; __syncthreads(); }
  float norm = sqrtf(red[0]) + 1e-8f;
  o[(size_t)row*128 + t] = v / norm;
}

// layer norm over D=768, one token per block (256 threads)
__global__ void k_ln(const float* __restrict__ x, const float* __restrict__ sc,
                     const float* __restrict__ bi, float* __restrict__ o){
  int tok = blockIdx.x; int t = threadIdx.x;
  __shared__ float red[256];
  const float* xr = x + (size_t)tok*768;
  float a0=xr[t], a1=xr[t+256], a2=xr[t+512];
  red[t] = a0+a1+a2; __syncthreads();
  for (int s=128; s>0; s>>=1){ if (t<s) red[t]+=red[t+s]; __syncthreads(); }
  float mean = red[0] * (1.f/768.f);
  __syncthreads();
  float d0=a0-mean, d1=a1-mean, d2=a2-mean;
  red[t] = d0*d0+d1*d1+d2*d2; __syncthreads();
  for (int s=128; s>0; s>>=1){ if (t<s) red[t]+=red[t+s]; __syncthreads(); }
  float den = sqrtf(red[0]*(1.f/768.f) + 1e-6f);
  float* orow = o + (size_t)tok*768;
  orow[t]     = d0/den*sc[t]     + bi[t];
  orow[t+256] = d1/den*sc[t+256] + bi[t+256];
  orow[t+512] = d2/den*sc[t+512] + bi[t+512];
}

// Tiled GEMM: out[M x N] = A[M x 768] @ W[768 x N] (+bias) (+res stride 768)
// 64x64 tiles, 256 threads; thread covers rows 4ty+r, cols tx+16j.
template<bool RES>
__global__ __launch_bounds__(256) void k_gemm(const float* __restrict__ A, const float* __restrict__ W,
                       const float* __restrict__ bias, const float* __restrict__ res,
                       float* __restrict__ out, int N){
  __shared__ float sA[64][68];
  __shared__ float sW[64][68];   // [d][col]
  int t = threadIdx.x;
  int nc0 = blockIdx.x << 6;
  int m0  = blockIdx.y << 6;
  int ty = t >> 4, tx = t & 15;
  float acc[4][4] = {{0.f}};
  for (int kc=0; kc<768; kc+=64){
    __syncthreads();
    #pragma unroll
    for (int i=0;i<4;i++){
      int idx = t + (i<<8); int r = idx>>4, c4=(idx&15)<<2;
      *(float4*)&sA[r][c4] = *(const float4*)(A + (size_t)(m0+r)*768 + kc + c4);
      *(float4*)&sW[r][c4] = *(const float4*)(W + (size_t)(kc+r)*N + nc0 + c4);
    }
    __syncthreads();
    #pragma unroll 2
    for (int d4=0; d4<64; d4+=4){
      float aa[4][4];
      #pragma unroll
      for (int r=0;r<4;r++){
        float4 a4 = *(const float4*)&sA[ty*4+r][d4];
        aa[r][0]=a4.x; aa[r][1]=a4.y; aa[r][2]=a4.z; aa[r][3]=a4.w;
      }
      #pragma unroll
      for (int dd=0; dd<4; dd++){
        float w0=sW[d4+dd][tx], w1=sW[d4+dd][tx+16], w2=sW[d4+dd][tx+32], w3=sW[d4+dd][tx+48];
        #pragma unroll
        for (int r=0;r<4;r++){
          acc[r][0]+=aa[r][dd]*w0; acc[r][1]+=aa[r][dd]*w1;
          acc[r][2]+=aa[r][dd]*w2; acc[r][3]+=aa[r][dd]*w3;
        }
      }
    }
  }
  #pragma unroll
  for (int r=0;r<4;r++){
    int row = m0 + ty*4 + r;
    #pragma unroll
    for (int j=0;j<4;j++){
      int col = nc0 + tx + 16*j;
      float v = acc[r][j];
      if (bias) v += bias[col];
      if (RES)  v += res[(size_t)row*768 + col];
      out[(size_t)row*N + col] = v;
    }
  }
}

// tau matvec: tout[tok, col] = xn[tok,:] @ tW[:, col] + tb[col]; 64*tc threads
__global__ void k_tau(const float* __restrict__ xn, const float* __restrict__ tW,
                      const float* __restrict__ tb, float* __restrict__ tout, int tc){
  int tok = blockIdx.x;
  int t = threadIdx.x;
  int col = t >> 6, lane = t & 63;
  const float* xr = xn + (size_t)tok*768;
  float v = 0.f;
  for (int d=lane; d<768; d+=64) v += xr[d]*tW[(size_t)d*tc + col];
  #pragma unroll
  for (int off=32; off; off>>=1) v += __shfl_down(v, off);
  if (lane==0) tout[(size_t)tok*tc + col] = v + tb[col];
}

// Tiled score GEMM + gate transform (64 tokens x 64 neurons per block), K=128 in 2 chunks.
__global__ __launch_bounds__(256) void k_score(const float* __restrict__ h, int hstride, int hoff,
                        const float* __restrict__ taub, int tstride, int toff,
                        const float* __restrict__ low,
                        float* __restrict__ outg, int n, int tok0){
  __shared__ float sh[64][68];
  __shared__ float sl[64][68];
  __shared__ float stau[64];
  int t = threadIdx.x;              // 256
  int nrow0 = blockIdx.x << 6;
  int trow0 = blockIdx.y << 6;      // within chunk
  int ty = t >> 4, tx = t & 15;
  if (t < 64) stau[t] = taub[(size_t)(tok0 + trow0 + t)*tstride + toff];
  float acc[4][4] = {{0.f}};
  for (int kc=0; kc<128; kc+=64){
    __syncthreads();
    #pragma unroll
    for (int i=0;i<4;i++){
      int idx = t + (i<<8); int r = idx>>4, c4=(idx&15)<<2;
      *(float4*)&sh[r][c4] = *(const float4*)(h + (size_t)(tok0+trow0+r)*hstride + hoff + kc + c4);
      *(float4*)&sl[r][c4] = *(const float4*)(low + (size_t)(nrow0+r)*128 + kc + c4);
    }
    __syncthreads();
    #pragma unroll 2
    for (int d4=0; d4<64; d4+=4){
      float4 ha[4], lb[4];
      #pragma unroll
      for (int r=0;r<4;r++) ha[r] = *(const float4*)&sh[ty*4+r][d4];
      #pragma unroll
      for (int j=0;j<4;j++) lb[j] = *(const float4*)&sl[tx+16*j][d4];
      #pragma unroll
      for (int r=0;r<4;r++){
        #pragma unroll
        for (int j=0;j<4;j++){
          acc[r][j] += ha[r].x*lb[j].x + ha[r].y*lb[j].y + ha[r].z*lb[j].z + ha[r].w*lb[j].w;
        }
      }
    }
  }
  #pragma unroll
  for (int i=0;i<4;i++){
    int tt = trow0 + ty*4 + i;      // within chunk
    float tau = stau[ty*4+i];
    #pragma unroll
    for (int j=0;j<4;j++){
      float raw = acc[i][j] - tau;
      float g = raw > 0.f ? raw : 1e-8f*expf(raw);
      outg[(size_t)tt*n + nrow0 + tx + 16*j] = expf(g) - 1.0f;  // exact ref math
    }
  }
}

// Top-K selection from a score row held in registers; normalization + aux sums.
template<int ITEMS, int K>
__global__ void k_select(const float* __restrict__ sc, int n, int tok0,
                         float* __restrict__ gval, int* __restrict__ gidx,
                         float* __restrict__ sums){
  int tl = blockIdx.x; int t = threadIdx.x; // 256
  float v[ITEMS];
  const float* row = sc + (size_t)tl*n;
  #pragma unroll
  for (int i=0;i<ITEMS;i++) v[i] = row[t + (i<<8)];
  __shared__ float wv[4]; __shared__ int wi[4];
  __shared__ float s0; __shared__ float stot;
  float myval = 0.f; int myidx = 0;
  int w = t >> 6, lane = t & 63;
  for (int it=0; it<K; it++){
    float mv = v[0]; int mi = t;
    #pragma unroll
    for (int i=1;i<ITEMS;i++){
      float vi = v[i];
      if (vi > mv){ mv = vi; mi = t + (i<<8); }
    }
    #pragma unroll
    for (int off=32; off; off>>=1){
      float ov = __shfl_xor(mv, off);
      int   oi = __shfl_xor(mi, off);
      if (ov > mv || (ov == mv && oi < mi)){ mv = ov; mi = oi; }
    }
    if (lane==0){ wv[w]=mv; wi[w]=mi; }
    __syncthreads();
    float bv = wv[0]; int bi = wi[0];
    #pragma unroll
    for (int k=1;k<4;k++){
      float ov=wv[k]; int oi=wi[k];
      if (ov > bv || (ov == bv && oi < bi)){ bv=ov; bi=oi; }
    }
    if (t == (bi & 255)){
      #pragma unroll
      for (int i=0;i<ITEMS;i++) if (i == (bi >> 8)) v[i] = -1.f;
    }
    if (t == it){ myval = bv; myidx = bi; }
    if (it==0 && t==0) s0 = tanhf(bv);
    __syncthreads();
  }
  float c = (t < K) ? myval : 0.f;
  #pragma unroll
  for (int off=32; off; off>>=1) c += __shfl_xor(c, off);
  if (lane==0) wv[w]=c;
  __syncthreads();
  if (t==0) stot = wv[0]+wv[1]+wv[2]+wv[3] + 1e-8f;
  __syncthreads();
  if (t < K){
    float nv = myval / stot * s0;
    size_t o = (size_t)(tok0 + tl)*K + t;
    gval[o] = nv; gidx[o] = myidx;
    atomicAdd(&sums[myidx], nv);
  }
}

// sparse sense-emit: out[tok,:] (+)= sum_k (xn[tok,:]·emb[idx_k]) * gval_k * w[idx_k,:]
__global__ void k_sense(const float* __restrict__ xn, const float* __restrict__ emb,
                        const float* __restrict__ w, const float* __restrict__ gval,
                        const int* __restrict__ gidx, float* __restrict__ out,
                        int K, int acc){
  int tok = blockIdx.x; int t = threadIdx.x; // 256
  __shared__ float sxn[768]; __shared__ float sact[64]; __shared__ int sidx[64];
  const float* xr = xn + (size_t)tok*768;
  if (t < 192) *(float4*)&sxn[t*4] = *(const float4*)(xr + t*4);
  if (t < K) sidx[t] = gidx[(size_t)tok*K + t];
  __syncthreads();
  int tpk = 256 / K;               // 8 (K=32) or 4 (K=64)
  int k = t / tpk, p = t % tpk;
  const float* er = emb + (size_t)sidx[k]*768;
  float v = 0.f;
  for (int d=p; d<768; d+=tpk) v += sxn[d]*er[d];
  for (int off=tpk>>1; off; off>>=1) v += __shfl_down(v, off);
  if (p==0) sact[k] = v * gval[(size_t)tok*K + k];
  __syncthreads();
  float* orow = out + (size_t)tok*768;
  for (int d=t; d<768; d+=256){
    float o = 0.f;
    for (int kk=0; kk<K; kk++) o += sact[kk]*w[(size_t)sidx[kk]*768 + d];
    if (acc) orow[d] += o; else orow[d] = o;
  }
}

// Tiled causal flash attention: one block = 64 q-rows x one head.
// Register-prefetched K/V, P written into K buffer, cols remapped c=tx+16j.
__global__ __launch_bounds__(256) void k_attn(const float* __restrict__ Q, const float* __restrict__ K,
                       const float* __restrict__ V, float* __restrict__ ao){
  __shared__ float sQ[64][68];
  __shared__ float sKP[64][68];   // K tile, then P (time-shared)
  __shared__ float sV[64][68];
  int flat = blockIdx.x + (blockIdx.y<<4) + blockIdx.z*192;   // 0..767
  int qt = (blockIdx.x + 5*(flat>>8)) & 15;   // scramble so co-resident blocks get mixed work
  int h = blockIdx.y, b = blockIdx.z;
  int t = threadIdx.x;
  int ty = t >> 4, tx = t & 15;
  size_t base = ((size_t)b*1024)*768 + (size_t)h*64;
  int q0 = qt << 6;
  #pragma unroll
  for (int i=0;i<4;i++){
    int idx = t + (i<<8); int r = idx>>4, c4 = (idx&15)<<2;
    *(float4*)&sQ[r][c4] = *(const float4*)(Q + base + (size_t)(q0+r)*768 + c4);
  }
  float4 kreg[4], vreg[4];
  #pragma unroll
  for (int i=0;i<4;i++){
    int idx = t + (i<<8); int r = idx>>4, c4=(idx&15)<<2;
    kreg[i] = *(const float4*)(K + base + (size_t)r*768 + c4);
    vreg[i] = *(const float4*)(V + base + (size_t)r*768 + c4);
  }
  float m[4], l[4], o[4][4];
  #pragma unroll
  for (int r=0;r<4;r++){
    m[r] = -INFINITY; l[r] = 0.f;
    #pragma unroll
    for (int j=0;j<4;j++) o[r][j] = 0.f;
  }
  for (int kt=0; kt<=qt; kt++){
    __syncthreads();                 // prev iter done with sKP(P)/sV; covers sQ staging at kt=0
    #pragma unroll
    for (int i=0;i<4;i++){
      int idx = t + (i<<8); int r = idx>>4, c4=(idx&15)<<2;
      *(float4*)&sKP[r][c4] = kreg[i];
      *(float4*)&sV[r][c4]  = vreg[i];
    }
    if (kt < qt){
      int t0n = (kt+1) << 6;
      #pragma unroll
      for (int i=0;i<4;i++){
        int idx = t + (i<<8); int r = idx>>4, c4=(idx&15)<<2;
        kreg[i] = *(const float4*)(K + base + (size_t)(t0n+r)*768 + c4);
        vreg[i] = *(const float4*)(V + base + (size_t)(t0n+r)*768 + c4);
      }
    }
    __syncthreads();                 // staging visible
    // S = Q K^T ; thread rows 4ty+r, cols tx+16j
    float s[4][4] = {{0.f}};
    #pragma unroll 2
    for (int d4=0; d4<64; d4+=4){
      float4 qa[4], kb[4];
      #pragma unroll
      for (int r=0;r<4;r++) qa[r] = *(const float4*)&sQ[ty*4+r][d4];
      #pragma unroll
      for (int j=0;j<4;j++) kb[j] = *(const float4*)&sKP[tx+16*j][d4];
      #pragma unroll
      for (int r=0;r<4;r++){
        #pragma unroll
        for (int j=0;j<4;j++){
          s[r][j] += qa[r].x*kb[j].x + qa[r].y*kb[j].y + qa[r].z*kb[j].z + qa[r].w*kb[j].w;
        }
      }
    }
    bool diag = (kt == qt);
    #pragma unroll
    for (int r=0;r<4;r++){
      int row = ty*4+r;
      #pragma unroll
      for (int j=0;j<4;j++){
        s[r][j] *= 0.125f;           // 1/sqrt(64)
        if (diag && (tx+16*j > row)) s[r][j] = -INFINITY;
      }
    }
    #pragma unroll
    for (int r=0;r<4;r++){
      float tm = fmaxf(fmaxf(s[r][0],s[r][1]), fmaxf(s[r][2],s[r][3]));
      #pragma unroll
      for (int off=8; off; off>>=1) tm = fmaxf(tm, __shfl_xor(tm, off));
      float mn = fmaxf(m[r], tm);
      float sc = expf(m[r] - mn);    // 0 on first tile
      float ps = 0.f;
      #pragma unroll
      for (int j=0;j<4;j++){
        float p = expf(s[r][j] - mn);
        s[r][j] = p; ps += p;
      }
      #pragma unroll
      for (int off=8; off; off>>=1) ps += __shfl_xor(ps, off);
      l[r] = l[r]*sc + ps;
      m[r] = mn;
      #pragma unroll
      for (int j=0;j<4;j++) o[r][j] *= sc;
    }
    __syncthreads();                 // all waves done reading K
    #pragma unroll
    for (int r=0;r<4;r++){
      #pragma unroll
      for (int j=0;j<4;j++) sKP[ty*4+r][tx+16*j] = s[r][j];
    }
    __syncthreads();                 // P visible
    #pragma unroll 2
    for (int k4=0; k4<64; k4+=4){
      float pas[4][4];
      #pragma unroll
      for (int r=0;r<4;r++){
        float4 tp = *(const float4*)&sKP[ty*4+r][k4];
        pas[r][0]=tp.x; pas[r][1]=tp.y; pas[r][2]=tp.z; pas[r][3]=tp.w;
      }
      #pragma unroll
      for (int kk=0; kk<4; kk++){
        float v0=sV[k4+kk][tx], v1=sV[k4+kk][tx+16], v2=sV[k4+kk][tx+32], v3=sV[k4+kk][tx+48];
        #pragma unroll
        for (int r=0;r<4;r++){
          o[r][0]+=pas[r][kk]*v0; o[r][1]+=pas[r][kk]*v1;
          o[r][2]+=pas[r][kk]*v2; o[r][3]+=pas[r][kk]*v3;
        }
      }
    }
  }
  #pragma unroll
  for (int r=0;r<4;r++){
    float inv = 1.f / l[r];
    #pragma unroll
    for (int j=0;j<4;j++)
      ao[base + (size_t)(q0+ty*4+r)*768 + tx + 16*j] = o[r][j]*inv;
  }
}

// aux = sum over gate types of ((mean - t)^2).sum() * n
__global__ void k_aux(const float* __restrict__ sums, float* __restrict__ out){
  int t = threadIdx.x; // 256
  __shared__ float red[256];
  float a = 0.f;
  const float inv = 1.f/4096.f;   // 1/(B*S)
  const float tq = 1.f/1024.f;
  for (int j=t; j<1024; j+=256){
    float d0 = sums[j]*inv        - tq; a += d0*d0*1024.f;
    float d1 = sums[1024+j]*inv   - tq; a += d1*d1*1024.f;
    float d2 = sums[2048+j]*inv   - tq; a += d2*d2*1024.f;
  }
  const float tk = 1.f/4096.f;
  for (int j=t; j<4096; j+=256){
    float d3 = sums[3072+j]*inv - tk; a += d3*d3*4096.f;
  }
  red[t]=a; __syncthreads();
  for (int s=128; s>0; s>>=1){ if (t<s) red[t]+=red[t+s]; __syncthreads(); }
  if (t==0) out[0] = red[0];
}

extern "C" void kernel_launch(void* const* d_in, const int* in_sizes, int n_in,
                              void* d_out, int out_size, void* d_ws, size_t ws_size,
                              hipStream_t stream){
  const float* x        = (const float*)d_in[0];
  const float* qk_emb   = (const float*)d_in[1];
  const float* qk_w     = (const float*)d_in[2];
  const float* v_emb    = (const float*)d_in[3];
  const float* v_w      = (const float*)d_in[4];
  const float* know_emb = (const float*)d_in[5];
  const float* know_w   = (const float*)d_in[6];
  const float* neuron_emb = (const float*)d_in[7];
  const float* pak  = (const float*)d_in[8];
  const float* pab  = (const float*)d_in[9];
  const float* pkk  = (const float*)d_in[10];
  const float* pkb  = (const float*)d_in[11];
  const float* tak  = (const float*)d_in[12];
  const float* tab  = (const float*)d_in[13];
  const float* tkk  = (const float*)d_in[14];
  const float* tkb  = (const float*)d_in[15];
  const float* expO = (const float*)d_in[16];
  const float* ln1s = (const float*)d_in[17];
  const float* ln1b = (const float*)d_in[18];
  const float* ln2s = (const float*)d_in[19];
  const float* ln2b = (const float*)d_in[20];
  float* out = (float*)d_out;
  float* ws  = (float*)d_ws;

  k_zero<<<28,256,0,stream>>>(ws+O_SUM, 7168);
  k_normemb<<<6144,128,0,stream>>>(neuron_emb, ws+O_EMBN);
  k_ln<<<4096,256,0,stream>>>(x, ln1s, ln1b, ws+O_XN);
  k_gemm<false><<<dim3(6,64),256,0,stream>>>(ws+O_XN, pak, pab, nullptr, ws+O_HALL, 384);
  k_tau<<<4096,192,0,stream>>>(ws+O_XN, tak, tab, ws+O_TAU, 3);

  // ---- attn gates: score (tiled GEMM) + select (register top-K) ----
  float* sc = ws + O_QB;
  k_score<<<dim3(16,64),256,0,stream>>>(ws+O_HALL,384,0,   ws+O_TAU,3,0, ws+O_EMBN, sc, 1024, 0);
  k_select<4,32><<<4096,256,0,stream>>>(sc, 1024, 0, ws+O_GVQ,(int*)(ws+O_GIQ), ws+O_SUM);
  k_score<<<dim3(16,64),256,0,stream>>>(ws+O_HALL,384,128, ws+O_TAU,3,1, ws+O_EMBN, sc, 1024, 0);
  k_select<4,32><<<4096,256,0,stream>>>(sc, 1024, 0, ws+O_GVK,(int*)(ws+O_GIK), ws+O_SUM+1024);
  k_score<<<dim3(16,64),256,0,stream>>>(ws+O_HALL,384,256, ws+O_TAU,3,2, ws+O_EMBN+1024*128, sc, 1024, 0);
  k_select<4,32><<<4096,256,0,stream>>>(sc, 1024, 0, ws+O_GVV,(int*)(ws+O_GIV), ws+O_SUM+2048);

  k_sense<<<4096,256,0,stream>>>(ws+O_XN, qk_emb, qk_w, ws+O_GVQ,(int*)(ws+O_GIQ), ws+O_QB, 32,0);
  k_sense<<<4096,256,0,stream>>>(ws+O_XN, qk_emb, qk_w, ws+O_GVK,(int*)(ws+O_GIK), ws+O_KB, 32,0);
  k_sense<<<4096,256,0,stream>>>(ws+O_XN, v_emb,  v_w,  ws+O_GVV,(int*)(ws+O_GIV), ws+O_VB, 32,0);

  // attention writes into XN region (xn1 no longer needed)
  k_attn<<<dim3(16,12,4),256,0,stream>>>(ws+O_QB, ws+O_KB, ws+O_VB, ws+O_XN);

  // x2 = x + attn_out @ expand_O  -> d_out (doubles as x2 buffer)
  k_gemm<true><<<dim3(12,64),256,0,stream>>>(ws+O_XN, expO, nullptr, x, out, 768);

  // LN2 -> xn2 in QB region
  k_ln<<<4096,256,0,stream>>>(out, ln2s, ln2b, ws+O_QB);
  k_gemm<false><<<dim3(2,64),256,0,stream>>>(ws+O_QB, pkk, pkb, nullptr, ws+O_HALL, 128);
  k_tau<<<4096,64,0,stream>>>(ws+O_QB, tkk, tkb, ws+O_TAUK, 1);

  // ---- know gate: 4 chunks of 1024 tokens; scores overlay KB region ----
  float* sck = ws + O_KB;
  for (int c=0; c<4; c++){
    int tok0 = c*1024;
    k_score<<<dim3(64,16),256,0,stream>>>(ws+O_HALL,128,0, ws+O_TAUK,1,0, ws+O_EMBN+2048*128, sck, 4096, tok0);
    k_select<16,64><<<1024,256,0,stream>>>(sck, 4096, tok0, ws+O_GVQ,(int*)(ws+O_GIQ), ws+O_SUM+3072);
  }

  // know sense-emit accumulates into d_out
  k_sense<<<4096,256,0,stream>>>(ws+O_QB, know_emb, know_w, ws+O_GVQ,(int*)(ws+O_GIQ), out, 64,1);

  k_aux<<<1,256,0,stream>>>(ws+O_SUM, out + 3145728);
}

// Round 7
// 1665.528 us; speedup vs baseline: 4.2002x; 1.1139x over previous
//
#include <hip/hip_runtime.h>
#include <math.h>

// Problem constants
// B=4, S=1024, D=768, d_space=128, n_qk=1024, n_v=1024, n_know=4096, H=12, dh=64
#define TOK 4096

// Workspace layout (float offsets)
#define O_EMBN   0            // 6144*128 = 786432  normalized neuron_emb
#define O_XN     786432       // 3145728  xn1 ; later reused as attention output
#define O_HALL   3932160      // 1572864  h_all (4096x384) ; later h_know (4096x128)
#define O_TAU    5505024      // 12288    tau_attn (4096x3)
#define O_TAUK   5517312      // 4096     tau_know
#define O_GVQ    5521408      // 131072   gate vals Q -> act Q (in place). know spans GVQ+GVK
#define O_GVK    5652480      // 131072   gate vals K -> act K
#define O_GVV    5783552      // 131072   gate vals V -> act V
#define O_GIQ    5914624      // 131072   gate idx Q (know idx spans GIQ+GIK)
#define O_GIK    6045696      // 131072
#define O_GIV    6176768      // 131072
#define O_QB     6307840      // 3145728  Q ; later xn2.  attn scores overlay QB..QB+4194304
#define O_KB     9453568      // 3145728  K.              know scores overlay KB..KB+4194304
#define O_VB     12599296     // 3145728  V
#define O_SUM    15745024     // 7168: sumQ[1024], sumK[1024], sumV[1024], sumKnow[4096]
// total 15752192 floats = 63.0 MB

__global__ void k_zero(float* p, int n){
  int i = blockIdx.x*blockDim.x + threadIdx.x;
  if (i < n) p[i] = 0.f;
}

// normalize neuron_emb rows (6144 x 128)
__global__ void k_normemb(const float* __restrict__ e, float* __restrict__ o){
  int row = blockIdx.x; int t = threadIdx.x; // 128 threads
  float v = e[(size_t)row*128 + t];
  __shared__ float red[128];
  red[t] = v*v; __syncthreads();
  for (int s=64; s>0; s>>=1){ if (t<s) red[t]+=red[t+s]; __syncthreads(); }
  float norm = sqrtf(red[0]) + 1e-8f;
  o[(size_t)row*128 + t] = v / norm;
}

// layer norm over D=768, one token per block (256 threads)
__global__ void k_ln(const float* __restrict__ x, const float* __restrict__ sc,
                     const float* __restrict__ bi, float* __restrict__ o){
  int tok = blockIdx.x; int t = threadIdx.x;
  __shared__ float red[256];
  const float* xr = x + (size_t)tok*768;
  float a0=xr[t], a1=xr[t+256], a2=xr[t+512];
  red[t] = a0+a1+a2; __syncthreads();
  for (int s=128; s>0; s>>=1){ if (t<s) red[t]+=red[t+s]; __syncthreads(); }
  float mean = red[0] * (1.f/768.f);
  __syncthreads();
  float d0=a0-mean, d1=a1-mean, d2=a2-mean;
  red[t] = d0*d0+d1*d1+d2*d2; __syncthreads();
  for (int s=128; s>0; s>>=1){ if (t<s) red[t]+=red[t+s]; __syncthreads(); }
  float den = sqrtf(red[0]*(1.f/768.f) + 1e-6f);
  float* orow = o + (size_t)tok*768;
  orow[t]     = d0/den*sc[t]     + bi[t];
  orow[t+256] = d1/den*sc[t+256] + bi[t+256];
  orow[t+512] = d2/den*sc[t+512] + bi[t+512];
}

// Tiled GEMM: out[M x N] = A[M x 768] @ W[768 x N] (+bias) (+res stride 768)
template<bool RES>
__global__ __launch_bounds__(256) void k_gemm(const float* __restrict__ A, const float* __restrict__ W,
                       const float* __restrict__ bias, const float* __restrict__ res,
                       float* __restrict__ out, int N){
  __shared__ float sA[64][68];
  __shared__ float sW[64][68];   // [d][col]
  int t = threadIdx.x;
  int nc0 = blockIdx.x << 6;
  int m0  = blockIdx.y << 6;
  int ty = t >> 4, tx = t & 15;
  float acc[4][4] = {{0.f}};
  for (int kc=0; kc<768; kc+=64){
    __syncthreads();
    #pragma unroll
    for (int i=0;i<4;i++){
      int idx = t + (i<<8); int r = idx>>4, c4=(idx&15)<<2;
      *(float4*)&sA[r][c4] = *(const float4*)(A + (size_t)(m0+r)*768 + kc + c4);
      *(float4*)&sW[r][c4] = *(const float4*)(W + (size_t)(kc+r)*N + nc0 + c4);
    }
    __syncthreads();
    #pragma unroll 2
    for (int d4=0; d4<64; d4+=4){
      float aa[4][4];
      #pragma unroll
      for (int r=0;r<4;r++){
        float4 a4 = *(const float4*)&sA[ty*4+r][d4];
        aa[r][0]=a4.x; aa[r][1]=a4.y; aa[r][2]=a4.z; aa[r][3]=a4.w;
      }
      #pragma unroll
      for (int dd=0; dd<4; dd++){
        float w0=sW[d4+dd][tx], w1=sW[d4+dd][tx+16], w2=sW[d4+dd][tx+32], w3=sW[d4+dd][tx+48];
        #pragma unroll
        for (int r=0;r<4;r++){
          acc[r][0]+=aa[r][dd]*w0; acc[r][1]+=aa[r][dd]*w1;
          acc[r][2]+=aa[r][dd]*w2; acc[r][3]+=aa[r][dd]*w3;
        }
      }
    }
  }
  #pragma unroll
  for (int r=0;r<4;r++){
    int row = m0 + ty*4 + r;
    #pragma unroll
    for (int j=0;j<4;j++){
      int col = nc0 + tx + 16*j;
      float v = acc[r][j];
      if (bias) v += bias[col];
      if (RES)  v += res[(size_t)row*768 + col];
      out[(size_t)row*N + col] = v;
    }
  }
}

// tau matvec: tout[tok, col] = xn[tok,:] @ tW[:, col] + tb[col]; 64*tc threads
__global__ void k_tau(const float* __restrict__ xn, const float* __restrict__ tW,
                      const float* __restrict__ tb, float* __restrict__ tout, int tc){
  int tok = blockIdx.x;
  int t = threadIdx.x;
  int col = t >> 6, lane = t & 63;
  const float* xr = xn + (size_t)tok*768;
  float v = 0.f;
  for (int d=lane; d<768; d+=64) v += xr[d]*tW[(size_t)d*tc + col];
  #pragma unroll
  for (int off=32; off; off>>=1) v += __shfl_down(v, off);
  if (lane==0) tout[(size_t)tok*tc + col] = v + tb[col];
}

// Tiled score GEMM + gate transform (64 tokens x 64 neurons per block), K=128 in 2 chunks.
__global__ __launch_bounds__(256) void k_score(const float* __restrict__ h, int hstride, int hoff,
                        const float* __restrict__ taub, int tstride, int toff,
                        const float* __restrict__ low,
                        float* __restrict__ outg, int n, int tok0){
  __shared__ float sh[64][68];
  __shared__ float sl[64][68];
  __shared__ float stau[64];
  int t = threadIdx.x;              // 256
  int nrow0 = blockIdx.x << 6;
  int trow0 = blockIdx.y << 6;      // within chunk
  int ty = t >> 4, tx = t & 15;
  if (t < 64) stau[t] = taub[(size_t)(tok0 + trow0 + t)*tstride + toff];
  float acc[4][4] = {{0.f}};
  for (int kc=0; kc<128; kc+=64){
    __syncthreads();
    #pragma unroll
    for (int i=0;i<4;i++){
      int idx = t + (i<<8); int r = idx>>4, c4=(idx&15)<<2;
      *(float4*)&sh[r][c4] = *(const float4*)(h + (size_t)(tok0+trow0+r)*hstride + hoff + kc + c4);
      *(float4*)&sl[r][c4] = *(const float4*)(low + (size_t)(nrow0+r)*128 + kc + c4);
    }
    __syncthreads();
    #pragma unroll 2
    for (int d4=0; d4<64; d4+=4){
      float4 ha[4], lb[4];
      #pragma unroll
      for (int r=0;r<4;r++) ha[r] = *(const float4*)&sh[ty*4+r][d4];
      #pragma unroll
      for (int j=0;j<4;j++) lb[j] = *(const float4*)&sl[tx+16*j][d4];
      #pragma unroll
      for (int r=0;r<4;r++){
        #pragma unroll
        for (int j=0;j<4;j++){
          acc[r][j] += ha[r].x*lb[j].x + ha[r].y*lb[j].y + ha[r].z*lb[j].z + ha[r].w*lb[j].w;
        }
      }
    }
  }
  #pragma unroll
  for (int i=0;i<4;i++){
    int tt = trow0 + ty*4 + i;      // within chunk
    float tau = stau[ty*4+i];
    #pragma unroll
    for (int j=0;j<4;j++){
      float raw = acc[i][j] - tau;
      float g = raw > 0.f ? raw : 1e-8f*expf(raw);
      outg[(size_t)tt*n + nrow0 + tx + 16*j] = expf(g) - 1.0f;  // exact ref math
    }
  }
}

// Top-K selection from a score row held in registers; normalization + aux sums.
template<int ITEMS, int K>
__global__ void k_select(const float* __restrict__ sc, int n, int tok0,
                         float* __restrict__ gval, int* __restrict__ gidx,
                         float* __restrict__ sums){
  int tl = blockIdx.x; int t = threadIdx.x; // 256
  float v[ITEMS];
  const float* row = sc + (size_t)tl*n;
  #pragma unroll
  for (int i=0;i<ITEMS;i++) v[i] = row[t + (i<<8)];
  __shared__ float wv[4]; __shared__ int wi[4];
  __shared__ float s0; __shared__ float stot;
  float myval = 0.f; int myidx = 0;
  int w = t >> 6, lane = t & 63;
  for (int it=0; it<K; it++){
    float mv = v[0]; int mi = t;
    #pragma unroll
    for (int i=1;i<ITEMS;i++){
      float vi = v[i];
      if (vi > mv){ mv = vi; mi = t + (i<<8); }
    }
    #pragma unroll
    for (int off=32; off; off>>=1){
      float ov = __shfl_xor(mv, off);
      int   oi = __shfl_xor(mi, off);
      if (ov > mv || (ov == mv && oi < mi)){ mv = ov; mi = oi; }
    }
    if (lane==0){ wv[w]=mv; wi[w]=mi; }
    __syncthreads();
    float bv = wv[0]; int bi = wi[0];
    #pragma unroll
    for (int k=1;k<4;k++){
      float ov=wv[k]; int oi=wi[k];
      if (ov > bv || (ov == bv && oi < bi)){ bv=ov; bi=oi; }
    }
    if (t == (bi & 255)){
      #pragma unroll
      for (int i=0;i<ITEMS;i++) if (i == (bi >> 8)) v[i] = -1.f;
    }
    if (t == it){ myval = bv; myidx = bi; }
    if (it==0 && t==0) s0 = tanhf(bv);
    __syncthreads();
  }
  float c = (t < K) ? myval : 0.f;
  #pragma unroll
  for (int off=32; off; off>>=1) c += __shfl_xor(c, off);
  if (lane==0) wv[w]=c;
  __syncthreads();
  if (t==0) stot = wv[0]+wv[1]+wv[2]+wv[3] + 1e-8f;
  __syncthreads();
  if (t < K){
    float nv = myval / stot * s0;
    size_t o = (size_t)(tok0 + tl)*K + t;
    gval[o] = nv; gidx[o] = myidx;
    atomicAdd(&sums[myidx], nv);
  }
}

// act phase: gval[tok,k] *= (xn[tok,:] . emb[idx_k,:])   (in-place; reads emb ONLY)
template<int K>
__global__ __launch_bounds__(256) void k_act(const float* __restrict__ xn, const float* __restrict__ emb,
                       float* __restrict__ gval, const int* __restrict__ gidx){
  int tok = blockIdx.x; int t = threadIdx.x; // 256
  __shared__ float sxn[768]; __shared__ int sidx[K];
  const float* xr = xn + (size_t)tok*768;
  if (t < 192) *(float4*)&sxn[t*4] = *(const float4*)(xr + t*4);
  if (t < K) sidx[t] = gidx[(size_t)tok*K + t];
  __syncthreads();
  const int tpk = 256 / K;           // 8 (K=32) or 4 (K=64)
  int k = t / tpk, p = t % tpk;
  const float4* er = (const float4*)(emb + (size_t)sidx[k]*768);
  float v = 0.f;
  #pragma unroll 4
  for (int i=p; i<192; i+=tpk){
    float4 e4 = er[i];
    float4 x4 = *(const float4*)&sxn[i*4];
    v += x4.x*e4.x + x4.y*e4.y + x4.z*e4.z + x4.w*e4.w;
  }
  #pragma unroll
  for (int off=tpk>>1; off; off>>=1) v += __shfl_down(v, off);
  if (p==0) gval[(size_t)tok*K + k] *= v;
}

// emit phase: out[tok,:] (+)= sum_k act_k * w[idx_k,:]   (reads w ONLY)
// 192 threads, each owns one float4 column.
template<int K, bool ACC>
__global__ __launch_bounds__(192) void k_emit(const float* __restrict__ w, const float* __restrict__ gval,
                        const int* __restrict__ gidx, float* __restrict__ out){
  int tok = blockIdx.x; int t = threadIdx.x; // 192
  __shared__ float sact[K]; __shared__ int sidx[K];
  if (t < K){ sact[t] = gval[(size_t)tok*K + t]; sidx[t] = gidx[(size_t)tok*K + t]; }
  __syncthreads();
  float4 o = {0.f,0.f,0.f,0.f};
  #pragma unroll 4
  for (int kk=0; kk<K; kk++){
    float a = sact[kk];
    float4 w4 = ((const float4*)(w + (size_t)sidx[kk]*768))[t];
    o.x += a*w4.x; o.y += a*w4.y; o.z += a*w4.z; o.w += a*w4.w;
  }
  float4* orow = (float4*)(out + (size_t)tok*768);
  if (ACC){
    float4 prev = orow[t];
    o.x+=prev.x; o.y+=prev.y; o.z+=prev.z; o.w+=prev.w;
  }
  orow[t] = o;
}

// Tiled causal flash attention: one block = 64 q-rows x one head.
// Register-prefetched K/V; V stored transposed in LDS so PV reads are float4.
__global__ __launch_bounds__(256) void k_attn(const float* __restrict__ Q, const float* __restrict__ K,
                       const float* __restrict__ V, float* __restrict__ ao){
  __shared__ float sQ[64][68];
  __shared__ float sKP[64][68];   // K tile, then P (time-shared)
  __shared__ float sVT[64][68];   // V transposed: sVT[col][k]
  int flat = blockIdx.x + (blockIdx.y<<4) + blockIdx.z*192;   // 0..767
  int qt = (blockIdx.x + 5*(flat>>8)) & 15;   // scramble so co-resident blocks get mixed work
  int h = blockIdx.y, b = blockIdx.z;
  int t = threadIdx.x;
  int ty = t >> 4, tx = t & 15;
  size_t base = ((size_t)b*1024)*768 + (size_t)h*64;
  int q0 = qt << 6;
  #pragma unroll
  for (int i=0;i<4;i++){
    int idx = t + (i<<8); int r = idx>>4, c4 = (idx&15)<<2;
    *(float4*)&sQ[r][c4] = *(const float4*)(Q + base + (size_t)(q0+r)*768 + c4);
  }
  float4 kreg[4], vreg[4];
  #pragma unroll
  for (int i=0;i<4;i++){
    int idx = t + (i<<8); int r = idx>>4, c4=(idx&15)<<2;
    kreg[i] = *(const float4*)(K + base + (size_t)r*768 + c4);
    vreg[i] = *(const float4*)(V + base + (size_t)r*768 + c4);
  }
  float m[4], l[4], o[4][4];
  #pragma unroll
  for (int r=0;r<4;r++){
    m[r] = -INFINITY; l[r] = 0.f;
    #pragma unroll
    for (int j=0;j<4;j++) o[r][j] = 0.f;
  }
  for (int kt=0; kt<=qt; kt++){
    __syncthreads();                 // prev iter done with sKP(P)/sVT; covers sQ staging at kt=0
    #pragma unroll
    for (int i=0;i<4;i++){
      int idx = t + (i<<8); int r = idx>>4, c4=(idx&15)<<2;
      *(float4*)&sKP[r][c4] = kreg[i];
      sVT[c4+0][r]=vreg[i].x; sVT[c4+1][r]=vreg[i].y;
      sVT[c4+2][r]=vreg[i].z; sVT[c4+3][r]=vreg[i].w;
    }
    if (kt < qt){
      int t0n = (kt+1) << 6;
      #pragma unroll
      for (int i=0;i<4;i++){
        int idx = t + (i<<8); int r = idx>>4, c4=(idx&15)<<2;
        kreg[i] = *(const float4*)(K + base + (size_t)(t0n+r)*768 + c4);
        vreg[i] = *(const float4*)(V + base + (size_t)(t0n+r)*768 + c4);
      }
    }
    __syncthreads();                 // staging visible
    // S = Q K^T ; thread rows 4ty+r, cols tx+16j
    float s[4][4] = {{0.f}};
    #pragma unroll 2
    for (int d4=0; d4<64; d4+=4){
      float4 qa[4], kb[4];
      #pragma unroll
      for (int r=0;r<4;r++) qa[r] = *(const float4*)&sQ[ty*4+r][d4];
      #pragma unroll
      for (int j=0;j<4;j++) kb[j] = *(const float4*)&sKP[tx+16*j][d4];
      #pragma unroll
      for (int r=0;r<4;r++){
        #pragma unroll
        for (int j=0;j<4;j++){
          s[r][j] += qa[r].x*kb[j].x + qa[r].y*kb[j].y + qa[r].z*kb[j].z + qa[r].w*kb[j].w;
        }
      }
    }
    bool diag = (kt == qt);
    #pragma unroll
    for (int r=0;r<4;r++){
      int row = ty*4+r;
      #pragma unroll
      for (int j=0;j<4;j++){
        s[r][j] *= 0.125f;           // 1/sqrt(64)
        if (diag && (tx+16*j > row)) s[r][j] = -INFINITY;
      }
    }
    #pragma unroll
    for (int r=0;r<4;r++){
      float tm = fmaxf(fmaxf(s[r][0],s[r][1]), fmaxf(s[r][2],s[r][3]));
      #pragma unroll
      for (int off=8; off; off>>=1) tm = fmaxf(tm, __shfl_xor(tm, off));
      float mn = fmaxf(m[r], tm);
      float sc = expf(m[r] - mn);    // 0 on first tile
      float ps = 0.f;
      #pragma unroll
      for (int j=0;j<4;j++){
        float p = expf(s[r][j] - mn);
        s[r][j] = p; ps += p;
      }
      #pragma unroll
      for (int off=8; off; off>>=1) ps += __shfl_xor(ps, off);
      l[r] = l[r]*sc + ps;
      m[r] = mn;
      #pragma unroll
      for (int j=0;j<4;j++) o[r][j] *= sc;
    }
    __syncthreads();                 // all waves done reading K
    #pragma unroll
    for (int r=0;r<4;r++){
      #pragma unroll
      for (int j=0;j<4;j++) sKP[ty*4+r][tx+16*j] = s[r][j];
    }
    __syncthreads();                 // P visible
    #pragma unroll 2
    for (int k4=0; k4<64; k4+=4){
      float4 pas[4], vb[4];
      #pragma unroll
      for (int r=0;r<4;r++) pas[r] = *(const float4*)&sKP[ty*4+r][k4];
      #pragma unroll
      for (int j=0;j<4;j++) vb[j] = *(const float4*)&sVT[tx+16*j][k4];
      #pragma unroll
      for (int r=0;r<4;r++){
        #pragma unroll
        for (int j=0;j<4;j++){
          o[r][j] += pas[r].x*vb[j].x + pas[r].y*vb[j].y + pas[r].z*vb[j].z + pas[r].w*vb[j].w;
        }
      }
    }
  }
  #pragma unroll
  for (int r=0;r<4;r++){
    float inv = 1.f / l[r];
    #pragma unroll
    for (int j=0;j<4;j++)
      ao[base + (size_t)(q0+ty*4+r)*768 + tx + 16*j] = o[r][j]*inv;
  }
}

// aux = sum over gate types of ((mean - t)^2).sum() * n
__global__ void k_aux(const float* __restrict__ sums, float* __restrict__ out){
  int t = threadIdx.x; // 256
  __shared__ float red[256];
  float a = 0.f;
  const float inv = 1.f/4096.f;   // 1/(B*S)
  const float tq = 1.f/1024.f;
  for (int j=t; j<1024; j+=256){
    float d0 = sums[j]*inv        - tq; a += d0*d0*1024.f;
    float d1 = sums[1024+j]*inv   - tq; a += d1*d1*1024.f;
    float d2 = sums[2048+j]*inv   - tq; a += d2*d2*1024.f;
  }
  const float tk = 1.f/4096.f;
  for (int j=t; j<4096; j+=256){
    float d3 = sums[3072+j]*inv - tk; a += d3*d3*4096.f;
  }
  red[t]=a; __syncthreads();
  for (int s=128; s>0; s>>=1){ if (t<s) red[t]+=red[t+s]; __syncthreads(); }
  if (t==0) out[0] = red[0];
}

extern "C" void kernel_launch(void* const* d_in, const int* in_sizes, int n_in,
                              void* d_out, int out_size, void* d_ws, size_t ws_size,
                              hipStream_t stream){
  const float* x        = (const float*)d_in[0];
  const float* qk_emb   = (const float*)d_in[1];
  const float* qk_w     = (const float*)d_in[2];
  const float* v_emb    = (const float*)d_in[3];
  const float* v_w      = (const float*)d_in[4];
  const float* know_emb = (const float*)d_in[5];
  const float* know_w   = (const float*)d_in[6];
  const float* neuron_emb = (const float*)d_in[7];
  const float* pak  = (const float*)d_in[8];
  const float* pab  = (const float*)d_in[9];
  const float* pkk  = (const float*)d_in[10];
  const float* pkb  = (const float*)d_in[11];
  const float* tak  = (const float*)d_in[12];
  const float* tab  = (const float*)d_in[13];
  const float* tkk  = (const float*)d_in[14];
  const float* tkb  = (const float*)d_in[15];
  const float* expO = (const float*)d_in[16];
  const float* ln1s = (const float*)d_in[17];
  const float* ln1b = (const float*)d_in[18];
  const float* ln2s = (const float*)d_in[19];
  const float* ln2b = (const float*)d_in[20];
  float* out = (float*)d_out;
  float* ws  = (float*)d_ws;

  k_zero<<<28,256,0,stream>>>(ws+O_SUM, 7168);
  k_normemb<<<6144,128,0,stream>>>(neuron_emb, ws+O_EMBN);
  k_ln<<<4096,256,0,stream>>>(x, ln1s, ln1b, ws+O_XN);
  k_gemm<false><<<dim3(6,64),256,0,stream>>>(ws+O_XN, pak, pab, nullptr, ws+O_HALL, 384);
  k_tau<<<4096,192,0,stream>>>(ws+O_XN, tak, tab, ws+O_TAU, 3);

  // ---- attn gates: score (tiled GEMM) + select (register top-K) ----
  float* sc = ws + O_QB;
  k_score<<<dim3(16,64),256,0,stream>>>(ws+O_HALL,384,0,   ws+O_TAU,3,0, ws+O_EMBN, sc, 1024, 0);
  k_select<4,32><<<4096,256,0,stream>>>(sc, 1024, 0, ws+O_GVQ,(int*)(ws+O_GIQ), ws+O_SUM);
  k_score<<<dim3(16,64),256,0,stream>>>(ws+O_HALL,384,128, ws+O_TAU,3,1, ws+O_EMBN, sc, 1024, 0);
  k_select<4,32><<<4096,256,0,stream>>>(sc, 1024, 0, ws+O_GVK,(int*)(ws+O_GIK), ws+O_SUM+1024);
  k_score<<<dim3(16,64),256,0,stream>>>(ws+O_HALL,384,256, ws+O_TAU,3,2, ws+O_EMBN+1024*128, sc, 1024, 0);
  k_select<4,32><<<4096,256,0,stream>>>(sc, 1024, 0, ws+O_GVV,(int*)(ws+O_GIV), ws+O_SUM+2048);

  // ---- act phase (reads emb tables only; Q/K share qk_emb -> L2-warm) ----
  k_act<32><<<4096,256,0,stream>>>(ws+O_XN, qk_emb, ws+O_GVQ,(int*)(ws+O_GIQ));
  k_act<32><<<4096,256,0,stream>>>(ws+O_XN, qk_emb, ws+O_GVK,(int*)(ws+O_GIK));
  k_act<32><<<4096,256,0,stream>>>(ws+O_XN, v_emb,  ws+O_GVV,(int*)(ws+O_GIV));
  // ---- emit phase (reads w tables only) ----
  k_emit<32,false><<<4096,192,0,stream>>>(qk_w, ws+O_GVQ,(int*)(ws+O_GIQ), ws+O_QB);
  k_emit<32,false><<<4096,192,0,stream>>>(qk_w, ws+O_GVK,(int*)(ws+O_GIK), ws+O_KB);
  k_emit<32,false><<<4096,192,0,stream>>>(v_w,  ws+O_GVV,(int*)(ws+O_GIV), ws+O_VB);

  // attention writes into XN region (xn1 no longer needed)
  k_attn<<<dim3(16,12,4),256,0,stream>>>(ws+O_QB, ws+O_KB, ws+O_VB, ws+O_XN);

  // x2 = x + attn_out @ expand_O  -> d_out (doubles as x2 buffer)
  k_gemm<true><<<dim3(12,64),256,0,stream>>>(ws+O_XN, expO, nullptr, x, out, 768);

  // LN2 -> xn2 in QB region
  k_ln<<<4096,256,0,stream>>>(out, ln2s, ln2b, ws+O_QB);
  k_gemm<false><<<dim3(2,64),256,0,stream>>>(ws+O_QB, pkk, pkb, nullptr, ws+O_HALL, 128);
  k_tau<<<4096,64,0,stream>>>(ws+O_QB, tkk, tkb, ws+O_TAUK, 1);

  // ---- know gate: 4 chunks of 1024 tokens; scores overlay KB region ----
  float* sck = ws + O_KB;
  for (int c=0; c<4; c++){
    int tok0 = c*1024;
    k_score<<<dim3(64,16),256,0,stream>>>(ws+O_HALL,128,0, ws+O_TAUK,1,0, ws+O_EMBN+2048*128, sck, 4096, tok0);
    k_select<16,64><<<1024,256,0,stream>>>(sck, 4096, tok0, ws+O_GVQ,(int*)(ws+O_GIQ), ws+O_SUM+3072);
  }

  // know act + emit (accumulates into d_out)
  k_act<64><<<4096,256,0,stream>>>(ws+O_QB, know_emb, ws+O_GVQ,(int*)(ws+O_GIQ));
  k_emit<64,true><<<4096,192,0,stream>>>(know_w, ws+O_GVQ,(int*)(ws+O_GIQ), out);

  k_aux<<<1,256,0,stream>>>(ws+O_SUM, out + 3145728);
}